// Round 1
// baseline (18711.563 us; speedup 1.0000x reference)
//
#include <hip/hip_runtime.h>
#include <hip/hip_bf16.h>

// ---- problem constants (fixed by the reference) ----
#define N_NODES   100000
#define N_EDGES   1600000
#define N_MEMB    150000
#define N_CLUST   40000
#define N_EDGESP  800000
#define NB        64
#define NH        128   // = F = H
#define NCLS      10

// ---- workspace layout (in floats) ----
// aggbuf : 12.8M   (node agg; later h; later cluster aggc + xc1)
// x1buf  : 12.8M   (x1; later hc; later hc2)
// x2buf  : 12.8M   (x2; later cluster aggc2 + xc2)
// cnt (N), cntc (C), cnt2 (C), cntb (B), g (B*128), flag
#define O_AGG   0u
#define O_X1    12800000u
#define O_X2    25600000u
#define O_CNT   38400000u
#define O_CNTC  38500000u
#define O_CNT2  38540000u
#define O_CNTB  38580000u
#define O_G     38580128u
#define O_FLAG  38588320u
// total ~38.59M floats = ~154.4 MB

__device__ __forceinline__ float bf2f(unsigned short u) {
  return __uint_as_float(((unsigned int)u) << 16);
}
__device__ __forceinline__ void unpack8(uint4 u, float* w) {
  w[0] = __uint_as_float(u.x << 16); w[1] = __uint_as_float(u.x & 0xFFFF0000u);
  w[2] = __uint_as_float(u.y << 16); w[3] = __uint_as_float(u.y & 0xFFFF0000u);
  w[4] = __uint_as_float(u.z << 16); w[5] = __uint_as_float(u.z & 0xFFFF0000u);
  w[6] = __uint_as_float(u.w << 16); w[7] = __uint_as_float(u.w & 0xFFFF0000u);
}

// Detect whether float inputs are bf16 (flag=1) or f32 (flag=0).
// bf16 N(0,1) data: all exponents <= ~0x81. f32 data read as ushorts: the
// even-index (low-half) words are mantissa bits -> ~50% have exponent > 0x85.
__global__ void probe_dtype(const unsigned short* __restrict__ x, int* __restrict__ flag) {
  if (blockIdx.x != 0 || threadIdx.x != 0) return;
  int wild = 0;
  for (int i = 0; i < 1024; i += 2) {
    int e = (x[i] >> 7) & 0xFF;
    if (e > 0x85) wild++;
  }
  *flag = (wild < 8) ? 1 : 0;
}

// scatter-mean numerator (+counts) for external-dtype x (bf16 or f32 by flag)
__global__ __launch_bounds__(256) void edge_agg_ext(
    const void* __restrict__ x, const int* __restrict__ src, const int* __restrict__ dst,
    float* __restrict__ agg, float* __restrict__ cnt, int nE, const int* __restrict__ flag) {
  int isb = *flag;
  long long t = (long long)blockIdx.x * 256 + threadIdx.x;
  if (t >= (long long)nE * 16) return;
  int e = (int)(t >> 4), c = (int)(t & 15);
  int s = src[e], d = dst[e];
  float v[8];
  if (isb) {
    uint4 u = *(const uint4*)((const unsigned short*)x + (((size_t)s) << 7) + (c << 3));
    unpack8(u, v);
  } else {
    const float* xr = (const float*)x + (((size_t)s) << 7) + (c << 3);
    float4 a = *(const float4*)xr, b = *(const float4*)(xr + 4);
    v[0]=a.x; v[1]=a.y; v[2]=a.z; v[3]=a.w; v[4]=b.x; v[5]=b.y; v[6]=b.z; v[7]=b.w;
  }
  float* ar = agg + (((size_t)d) << 7) + (c << 3);
#pragma unroll
  for (int j = 0; j < 8; ++j) atomicAdd(ar + j, v[j]);
  if (c == 0 && cnt) atomicAdd(cnt + d, 1.0f);
}

// scatter-mean numerator (+counts) for internal f32 rows
__global__ __launch_bounds__(256) void edge_agg_f32(
    const float* __restrict__ x, const int* __restrict__ src, const int* __restrict__ dst,
    float* __restrict__ agg, float* __restrict__ cnt, int nE) {
  long long t = (long long)blockIdx.x * 256 + threadIdx.x;
  if (t >= (long long)nE * 16) return;
  int e = (int)(t >> 4), c = (int)(t & 15);
  int s = src[e], d = dst[e];
  const float* xr = x + (((size_t)s) << 7) + (c << 3);
  float4 a = *(const float4*)xr, b = *(const float4*)(xr + 4);
  float* ar = agg + (((size_t)d) << 7) + (c << 3);
  atomicAdd(ar + 0, a.x); atomicAdd(ar + 1, a.y); atomicAdd(ar + 2, a.z); atomicAdd(ar + 3, a.w);
  atomicAdd(ar + 4, b.x); atomicAdd(ar + 5, b.y); atomicAdd(ar + 6, b.z); atomicAdd(ar + 7, b.w);
  if (c == 0 && cnt) atomicAdd(cnt + d, 1.0f);
}

// out = relu( rowscale(A, cnt) @ Wl + bl + X @ Wr )   all matrices [128,128]
// A: f32. X: f32, or external dtype when xExt. Wl/bl/Wr: external dtype.
// Wr actual pointer = Wrv advanced by wrOff ELEMENTS (handles lin_W[128:256]).
__global__ __launch_bounds__(256) void conv_fused(
    const float* __restrict__ A, const float* __restrict__ cnt,
    const void* __restrict__ X, int xExt,
    const void* __restrict__ Wlv, const void* __restrict__ blv,
    const void* __restrict__ Wrv, int wrOff,
    float* __restrict__ out, int nrows, const int* __restrict__ flag) {
  int isb = *flag;
  __shared__ float sA[32][129];
  __shared__ float sX[32][129];
  int tid = threadIdx.x;
  int row0 = blockIdx.x * 32;

  const unsigned short* Wl_b = (const unsigned short*)Wlv;
  const float*          Wl_f = (const float*)Wlv;
  const unsigned short* Wr_b = (const unsigned short*)Wrv + wrOff;
  const float*          Wr_f = (const float*)Wrv + wrOff;

  // stage A (scaled by 1/max(cnt,1))
  for (int i = tid; i < 1024; i += 256) {
    int r = i >> 5, c4 = (i & 31) << 2;
    int gr = row0 + r;
    float4 v = make_float4(0.f, 0.f, 0.f, 0.f);
    float sc = 1.0f;
    if (gr < nrows) {
      v = ((const float4*)(A + (((size_t)gr) << 7)))[i & 31];
      if (cnt) sc = 1.0f / fmaxf(cnt[gr], 1.0f);
    }
    sA[r][c4 + 0] = v.x * sc; sA[r][c4 + 1] = v.y * sc;
    sA[r][c4 + 2] = v.z * sc; sA[r][c4 + 3] = v.w * sc;
  }
  // stage X
  for (int i = tid; i < 1024; i += 256) {
    int r = i >> 5, c4 = (i & 31) << 2;
    int gr = row0 + r;
    float4 v = make_float4(0.f, 0.f, 0.f, 0.f);
    if (gr < nrows) {
      if (xExt && isb) {
        uint2 u = *(const uint2*)((const unsigned short*)X + (((size_t)gr) << 7) + c4);
        v.x = __uint_as_float(u.x << 16); v.y = __uint_as_float(u.x & 0xFFFF0000u);
        v.z = __uint_as_float(u.y << 16); v.w = __uint_as_float(u.y & 0xFFFF0000u);
      } else {
        v = ((const float4*)X)[(((size_t)gr) << 5) + (i & 31)];
      }
    }
    sX[r][c4 + 0] = v.x; sX[r][c4 + 1] = v.y; sX[r][c4 + 2] = v.z; sX[r][c4 + 3] = v.w;
  }
  __syncthreads();

  int cg = tid & 15, rb = tid >> 4;
  float acc0[8], acc1[8];
#pragma unroll
  for (int j = 0; j < 8; ++j) { acc0[j] = 0.f; acc1[j] = 0.f; }

  if (isb) {
    for (int k = 0; k < 128; ++k) {
      float a0 = sA[rb][k], a1 = sA[rb + 16][k];
      float xv0 = sX[rb][k], xv1 = sX[rb + 16][k];
      uint4 ul = *(const uint4*)(Wl_b + (k << 7) + (cg << 3));
      uint4 ur = *(const uint4*)(Wr_b + (k << 7) + (cg << 3));
      float wl[8], wr[8];
      unpack8(ul, wl); unpack8(ur, wr);
#pragma unroll
      for (int j = 0; j < 8; ++j) {
        acc0[j] = fmaf(a0, wl[j], acc0[j]); acc0[j] = fmaf(xv0, wr[j], acc0[j]);
        acc1[j] = fmaf(a1, wl[j], acc1[j]); acc1[j] = fmaf(xv1, wr[j], acc1[j]);
      }
    }
  } else {
    for (int k = 0; k < 128; ++k) {
      float a0 = sA[rb][k], a1 = sA[rb + 16][k];
      float xv0 = sX[rb][k], xv1 = sX[rb + 16][k];
      const float* wlp = Wl_f + (k << 7) + (cg << 3);
      const float* wrp = Wr_f + (k << 7) + (cg << 3);
      float4 l0 = *(const float4*)wlp, l1 = *(const float4*)(wlp + 4);
      float4 r0 = *(const float4*)wrp, r1 = *(const float4*)(wrp + 4);
      float wl[8] = {l0.x, l0.y, l0.z, l0.w, l1.x, l1.y, l1.z, l1.w};
      float wr[8] = {r0.x, r0.y, r0.z, r0.w, r1.x, r1.y, r1.z, r1.w};
#pragma unroll
      for (int j = 0; j < 8; ++j) {
        acc0[j] = fmaf(a0, wl[j], acc0[j]); acc0[j] = fmaf(xv0, wr[j], acc0[j]);
        acc1[j] = fmaf(a1, wl[j], acc1[j]); acc1[j] = fmaf(xv1, wr[j], acc1[j]);
      }
    }
  }

  // bias + relu + store
  float bs[8];
  if (isb) {
    uint4 u = *(const uint4*)((const unsigned short*)blv + (cg << 3));
    unpack8(u, bs);
  } else {
    const float* bp = (const float*)blv + (cg << 3);
    float4 f0 = *(const float4*)bp, f1 = *(const float4*)(bp + 4);
    bs[0]=f0.x; bs[1]=f0.y; bs[2]=f0.z; bs[3]=f0.w; bs[4]=f1.x; bs[5]=f1.y; bs[6]=f1.z; bs[7]=f1.w;
  }
  int gr0 = row0 + rb;
  if (gr0 < nrows) {
    float* o = out + (((size_t)gr0) << 7) + (cg << 3);
    float4 o0, o1;
    o0.x = fmaxf(acc0[0] + bs[0], 0.f); o0.y = fmaxf(acc0[1] + bs[1], 0.f);
    o0.z = fmaxf(acc0[2] + bs[2], 0.f); o0.w = fmaxf(acc0[3] + bs[3], 0.f);
    o1.x = fmaxf(acc0[4] + bs[4], 0.f); o1.y = fmaxf(acc0[5] + bs[5], 0.f);
    o1.z = fmaxf(acc0[6] + bs[6], 0.f); o1.w = fmaxf(acc0[7] + bs[7], 0.f);
    *(float4*)o = o0; *(float4*)(o + 4) = o1;
  }
  int gr1 = row0 + rb + 16;
  if (gr1 < nrows) {
    float* o = out + (((size_t)gr1) << 7) + (cg << 3);
    float4 o0, o1;
    o0.x = fmaxf(acc1[0] + bs[0], 0.f); o0.y = fmaxf(acc1[1] + bs[1], 0.f);
    o0.z = fmaxf(acc1[2] + bs[2], 0.f); o0.w = fmaxf(acc1[3] + bs[3], 0.f);
    o1.x = fmaxf(acc1[4] + bs[4], 0.f); o1.y = fmaxf(acc1[5] + bs[5], 0.f);
    o1.z = fmaxf(acc1[6] + bs[6], 0.f); o1.w = fmaxf(acc1[7] + bs[7], 0.f);
    *(float4*)o = o0; *(float4*)(o + 4) = o1;
  }
}

__global__ __launch_bounds__(256) void rowdiv(float* __restrict__ v, const float* __restrict__ cnt, int nrows) {
  int t = blockIdx.x * 256 + threadIdx.x;
  if (t >= nrows * 32) return;
  int r = t >> 5;
  float sc = 1.0f / fmaxf(cnt[r], 1.0f);
  float4* p = (float4*)(v + (((size_t)r) << 7)) + (t & 31);
  float4 x = *p;
  x.x *= sc; x.y *= sc; x.z *= sc; x.w *= sc;
  *p = x;
}

__global__ __launch_bounds__(256) void pool_rows(
    const float* __restrict__ vals, const int* __restrict__ idx,
    float* __restrict__ osum, float* __restrict__ ocnt, int nrows) {
  long long t = (long long)blockIdx.x * 256 + threadIdx.x;
  if (t >= (long long)nrows * 16) return;
  int r = (int)(t >> 4), c = (int)(t & 15);
  int b = idx[r];
  const float* vr = vals + (((size_t)r) << 7) + (c << 3);
  float4 a = *(const float4*)vr, bb = *(const float4*)(vr + 4);
  float* o = osum + (((size_t)b) << 7) + (c << 3);
  atomicAdd(o + 0, a.x); atomicAdd(o + 1, a.y); atomicAdd(o + 2, a.z); atomicAdd(o + 3, a.w);
  atomicAdd(o + 4, bb.x); atomicAdd(o + 5, bb.y); atomicAdd(o + 6, bb.z); atomicAdd(o + 7, bb.w);
  if (c == 0) atomicAdd(ocnt + b, 1.0f);
}

__global__ void final_head(const float* __restrict__ g, const float* __restrict__ cntb,
                           const void* __restrict__ W, const void* __restrict__ bias,
                           void* __restrict__ out, const int* __restrict__ flag) {
  int isb = *flag;
  int b = blockIdx.x, l = threadIdx.x;
  __shared__ float lg[16];
  float sc = 1.0f / fmaxf(cntb[b], 1.0f);
  if (l < NCLS) {
    float acc = isb ? bf2f(((const unsigned short*)bias)[l]) : ((const float*)bias)[l];
    for (int k = 0; k < NH; ++k) {
      float w = isb ? bf2f(((const unsigned short*)W)[k * NCLS + l]) : ((const float*)W)[k * NCLS + l];
      acc += g[b * NH + k] * sc * w;
    }
    lg[l] = acc;
  }
  __syncthreads();
  if (l == 0) {
    float m = lg[0];
    for (int c = 1; c < NCLS; ++c) m = fmaxf(m, lg[c]);
    float se = 0.f;
    for (int c = 0; c < NCLS; ++c) se += expf(lg[c] - m);
    float lse = logf(se) + m;
    for (int c = 0; c < NCLS; ++c) {
      float o = lg[c] - lse;
      if (isb) ((__hip_bfloat16*)out)[b * NCLS + c] = __float2bfloat16(o);
      else     ((float*)out)[b * NCLS + c] = o;
    }
  }
}

extern "C" void kernel_launch(void* const* d_in, const int* in_sizes, int n_in,
                              void* d_out, int out_size, void* d_ws, size_t ws_size,
                              hipStream_t stream) {
  (void)in_sizes; (void)n_in; (void)out_size; (void)ws_size;
  const void* x        = d_in[0];
  const int*  ei       = (const int*)d_in[1];
  const int*  src      = ei;
  const int*  dst      = ei + N_EDGES;
  const int*  ci       = (const int*)d_in[3];
  const int*  cn       = ci;              // cover: node ids
  const int*  cc       = ci + N_MEMB;     // cover: cluster ids
  const int*  eip      = (const int*)d_in[4];
  const int*  srcp     = eip;
  const int*  dstp     = eip + N_EDGESP;
  const int*  batch_c  = (const int*)d_in[5];
  const void* lin2_W   = d_in[6];
  const void* lin2_b   = d_in[7];
  const void* in_c1_Wl = d_in[8];  const void* in_c1_bl = d_in[9];  const void* in_c1_Wr = d_in[10];
  const void* in_c2_Wl = d_in[11]; const void* in_c2_bl = d_in[12]; const void* in_c2_Wr = d_in[13];
  const void* in_lin_W = d_in[14]; const void* in_lin_b = d_in[15];
  const void* b1_c1_Wl = d_in[16]; const void* b1_c1_bl = d_in[17]; const void* b1_c1_Wr = d_in[18];
  const void* b1_c2_Wl = d_in[19]; const void* b1_c2_bl = d_in[20]; const void* b1_c2_Wr = d_in[21];
  const void* b1_lin_W = d_in[22]; const void* b1_lin_b = d_in[23];

  float* ws   = (float*)d_ws;
  float* agg  = ws + O_AGG;
  float* x1b  = ws + O_X1;
  float* x2b  = ws + O_X2;
  float* cnt  = ws + O_CNT;
  float* cntc = ws + O_CNTC;
  float* cnt2 = ws + O_CNT2;
  float* cntb = ws + O_CNTB;
  float* g    = ws + O_G;
  int*   flag = (int*)(ws + O_FLAG);

  // buffer reuse map
  float* h     = agg;                 // node block output
  float* hc    = x1b;                 // pooled cluster features
  float* aggc  = agg;                 // cluster conv1 agg
  float* xc1   = agg + 5120000;       // cluster conv1 out
  float* aggc2 = x2b;                 // cluster conv2 agg
  float* xc2   = x2b + 5120000;       // cluster conv2 out
  float* hc2   = x1b;                 // cluster block output

  probe_dtype<<<1, 64, 0, stream>>>((const unsigned short*)x, flag);

  // ---- node block: conv1 ----
  hipMemsetAsync(agg, 0, (size_t)N_NODES * 128 * 4, stream);
  hipMemsetAsync(cnt, 0, (size_t)N_NODES * 4, stream);
  edge_agg_ext<<<(N_EDGES * 16) / 256, 256, 0, stream>>>(x, src, dst, agg, cnt, N_EDGES, flag);
  conv_fused<<<N_NODES / 32, 256, 0, stream>>>(agg, cnt, x, 1, in_c1_Wl, in_c1_bl, in_c1_Wr, 0, x1b, N_NODES, flag);
  // ---- node block: conv2 (same dst -> same counts, reuse cnt) ----
  hipMemsetAsync(agg, 0, (size_t)N_NODES * 128 * 4, stream);
  edge_agg_f32<<<(N_EDGES * 16) / 256, 256, 0, stream>>>(x1b, src, dst, agg, nullptr, N_EDGES);
  conv_fused<<<N_NODES / 32, 256, 0, stream>>>(agg, cnt, x1b, 0, in_c2_Wl, in_c2_bl, in_c2_Wr, 0, x2b, N_NODES, flag);
  // ---- node block: lin (concat) -> h (into agg buffer) ----
  conv_fused<<<N_NODES / 32, 256, 0, stream>>>(x1b, nullptr, x2b, 0, in_lin_W, in_lin_b, in_lin_W, 16384, h, N_NODES, flag);

  // ---- cover pool: h -> hc ----
  hipMemsetAsync(hc, 0, (size_t)N_CLUST * 128 * 4, stream);
  hipMemsetAsync(cntc, 0, (size_t)N_CLUST * 4, stream);
  edge_agg_f32<<<(N_MEMB * 16) / 256, 256, 0, stream>>>(h, cn, cc, hc, cntc, N_MEMB);
  rowdiv<<<(N_CLUST * 32) / 256, 256, 0, stream>>>(hc, cntc, N_CLUST);

  // ---- cluster block: conv1 ----
  hipMemsetAsync(aggc, 0, (size_t)N_CLUST * 128 * 4, stream);
  hipMemsetAsync(cnt2, 0, (size_t)N_CLUST * 4, stream);
  edge_agg_f32<<<(N_EDGESP * 16) / 256, 256, 0, stream>>>(hc, srcp, dstp, aggc, cnt2, N_EDGESP);
  conv_fused<<<N_CLUST / 32, 256, 0, stream>>>(aggc, cnt2, hc, 0, b1_c1_Wl, b1_c1_bl, b1_c1_Wr, 0, xc1, N_CLUST, flag);
  // ---- cluster block: conv2 ----
  hipMemsetAsync(aggc2, 0, (size_t)N_CLUST * 128 * 4, stream);
  edge_agg_f32<<<(N_EDGESP * 16) / 256, 256, 0, stream>>>(xc1, srcp, dstp, aggc2, nullptr, N_EDGESP);
  conv_fused<<<N_CLUST / 32, 256, 0, stream>>>(aggc2, cnt2, xc1, 0, b1_c2_Wl, b1_c2_bl, b1_c2_Wr, 0, xc2, N_CLUST, flag);
  // ---- cluster block: lin -> hc2 ----
  conv_fused<<<N_CLUST / 32, 256, 0, stream>>>(xc1, nullptr, xc2, 0, b1_lin_W, b1_lin_b, b1_lin_W, 16384, hc2, N_CLUST, flag);

  // ---- global mean pool + head ----
  hipMemsetAsync(cntb, 0, (size_t)(O_G + NB * 128 - O_CNTB) * 4, stream);
  pool_rows<<<(N_CLUST * 16) / 256, 256, 0, stream>>>(hc2, batch_c, g, cntb, N_CLUST);
  final_head<<<NB, 64, 0, stream>>>(g, cntb, lin2_W, lin2_b, d_out, flag);
}

// Round 2
// 1814.822 us; speedup vs baseline: 10.3104x; 10.3104x over previous
//
#include <hip/hip_runtime.h>
#include <hip/hip_bf16.h>

// ---- problem constants (fixed by the reference) ----
#define N_NODES   100000
#define N_EDGES   1600000
#define N_MEMB    150000
#define N_CLUST   40000
#define N_EDGESP  800000
#define NB        64
#define NH        128
#define NCLS      10

// ---- workspace layout ----
// float arena: 3 x 12.8M floats, then int region, then g
#define O_AGG   0u
#define O_X1    12800000u
#define O_X2    25600000u
#define O_INT   38400000u          // start of int region (float-offset)
// int region offsets (in ints, relative to (int*)(ws + O_INT))
#define I_NRP   0u                 // node rowptr, N+1
#define I_NCUR  100004u            // node deg/cursor, N
#define I_NCOL  200008u            // node cols, E
#define I_CRP   1800008u           // cluster rowptr, C+1
#define I_CCUR  1840012u           // cluster cursor, C
#define I_CCOL  1880012u           // cluster cols, E2
#define I_MRP   2680012u           // membership rowptr, C+1
#define I_MCUR  2720016u           // membership cursor, C
#define I_MCOL  2760016u           // membership cols, M
#define I_BSUM  2910016u           // scan block sums (<=64)
#define I_FLAG  2910080u           // dtype flag
#define O_G     41310176u          // g: B*128 floats
// total ~41.32M floats ~= 165.3 MB

__device__ __forceinline__ float bf2f(unsigned short u) {
  return __uint_as_float(((unsigned int)u) << 16);
}
__device__ __forceinline__ void unpack8(uint4 u, float* w) {
  w[0] = __uint_as_float(u.x << 16); w[1] = __uint_as_float(u.x & 0xFFFF0000u);
  w[2] = __uint_as_float(u.y << 16); w[3] = __uint_as_float(u.y & 0xFFFF0000u);
  w[4] = __uint_as_float(u.z << 16); w[5] = __uint_as_float(u.z & 0xFFFF0000u);
  w[6] = __uint_as_float(u.w << 16); w[7] = __uint_as_float(u.w & 0xFFFF0000u);
}

// Detect whether "float" inputs are actually bf16 (flag=1) or f32 (flag=0).
__global__ void probe_dtype(const unsigned short* __restrict__ x, int* __restrict__ flag) {
  if (blockIdx.x != 0 || threadIdx.x != 0) return;
  int wild = 0;
  for (int i = 0; i < 1024; i += 2) {
    int e = (x[i] >> 7) & 0xFF;
    if (e > 0x85) wild++;
  }
  *flag = (wild < 8) ? 1 : 0;
}

// ============ CSR build ============
__global__ __launch_bounds__(256) void count_deg(const int* __restrict__ dstI, int* __restrict__ deg, int nE) {
  int t = blockIdx.x * 256 + threadIdx.x;
  if (t < nE) atomicAdd(&deg[dstI[t]], 1);
}

#define SCAN_CHUNK 2048
__global__ __launch_bounds__(256) void scan_bsum(const int* __restrict__ v, int* __restrict__ bsum, int n) {
  __shared__ int sw[4];
  int tid = threadIdx.x;
  int base = blockIdx.x * SCAN_CHUNK + tid * 8;
  int s = 0;
#pragma unroll
  for (int j = 0; j < 8; ++j) { int i = base + j; s += (i < n) ? v[i] : 0; }
  for (int off = 32; off; off >>= 1) s += __shfl_down(s, off);
  if ((tid & 63) == 0) sw[tid >> 6] = s;
  __syncthreads();
  if (tid == 0) bsum[blockIdx.x] = sw[0] + sw[1] + sw[2] + sw[3];
}

__global__ void scan_top(int* __restrict__ bsum, int nb) {
  int lane = threadIdx.x;
  int v = (lane < nb) ? bsum[lane] : 0;
  int inc = v;
  for (int off = 1; off < 64; off <<= 1) {
    int u = __shfl_up(inc, off);
    if (lane >= off) inc += u;
  }
  if (lane < nb) bsum[lane] = inc - v;
}

__global__ __launch_bounds__(256) void scan_write(const int* __restrict__ v, const int* __restrict__ bsum,
                                                  int* __restrict__ rowptr, int n, int total) {
  __shared__ int sw[4];
  int tid = threadIdx.x, lane = tid & 63, wv = tid >> 6;
  int base = blockIdx.x * SCAN_CHUNK + tid * 8;
  int x[8]; int s = 0;
#pragma unroll
  for (int j = 0; j < 8; ++j) { int i = base + j; int t = (i < n) ? v[i] : 0; x[j] = s; s += t; }
  int inc = s;
  for (int off = 1; off < 64; off <<= 1) {
    int u = __shfl_up(inc, off);
    if (lane >= off) inc += u;
  }
  int wexcl = inc - s;
  if (lane == 63) sw[wv] = inc;
  __syncthreads();
  int woff = 0;
  for (int k = 0; k < wv; ++k) woff += sw[k];
  int off0 = bsum[blockIdx.x] + woff + wexcl;
#pragma unroll
  for (int j = 0; j < 8; ++j) { int i = base + j; if (i < n) rowptr[i] = off0 + x[j]; }
  if (blockIdx.x == 0 && tid == 0) rowptr[n] = total;
}

__global__ __launch_bounds__(256) void copy_int(const int* __restrict__ a, int* __restrict__ b, int n) {
  int t = blockIdx.x * 256 + threadIdx.x;
  if (t < n) b[t] = a[t];
}

__global__ __launch_bounds__(256) void fill_csr(const int* __restrict__ srcI, const int* __restrict__ dstI,
                                                int* __restrict__ cur, int* __restrict__ col, int nE) {
  int t = blockIdx.x * 256 + threadIdx.x;
  if (t < nE) { int p = atomicAdd(&cur[dstI[t]], 1); col[p] = srcI[t]; }
}

// ============ pull-mode mean aggregation ============
// one wave per destination row; lane owns 2 consecutive features
__global__ __launch_bounds__(256) void gather_mean_f32(
    const float* __restrict__ x, const int* __restrict__ rowptr, const int* __restrict__ col,
    float* __restrict__ out, int n) {
  int w = (blockIdx.x * 256 + threadIdx.x) >> 6;
  if (w >= n) return;
  int lane = threadIdx.x & 63;
  int s0 = rowptr[w], s1 = rowptr[w + 1];
  const float2* xb = (const float2*)x;
  float ax = 0.f, ay = 0.f, bx = 0.f, by = 0.f;
  int j = s0;
  for (; j + 1 < s1; j += 2) {
    int sA = col[j], sB = col[j + 1];
    float2 vA = xb[((size_t)sA << 6) + lane];
    float2 vB = xb[((size_t)sB << 6) + lane];
    ax += vA.x; ay += vA.y; bx += vB.x; by += vB.y;
  }
  if (j < s1) {
    int sA = col[j];
    float2 vA = xb[((size_t)sA << 6) + lane];
    ax += vA.x; ay += vA.y;
  }
  float sc = (s1 > s0) ? 1.0f / (float)(s1 - s0) : 0.f;
  ((float2*)out)[((size_t)w << 6) + lane] = make_float2((ax + bx) * sc, (ay + by) * sc);
}

__global__ __launch_bounds__(256) void gather_mean_ext(
    const void* __restrict__ x, const int* __restrict__ rowptr, const int* __restrict__ col,
    float* __restrict__ out, int n, const int* __restrict__ flag) {
  int isb = *flag;
  int w = (blockIdx.x * 256 + threadIdx.x) >> 6;
  if (w >= n) return;
  int lane = threadIdx.x & 63;
  int s0 = rowptr[w], s1 = rowptr[w + 1];
  float ax = 0.f, ay = 0.f;
  if (isb) {
    const unsigned* xb = (const unsigned*)x;
    for (int j = s0; j < s1; ++j) {
      unsigned u = xb[((size_t)col[j] << 6) + lane];
      ax += __uint_as_float(u << 16);
      ay += __uint_as_float(u & 0xFFFF0000u);
    }
  } else {
    const float2* xb = (const float2*)x;
    for (int j = s0; j < s1; ++j) {
      float2 v = xb[((size_t)col[j] << 6) + lane];
      ax += v.x; ay += v.y;
    }
  }
  float sc = (s1 > s0) ? 1.0f / (float)(s1 - s0) : 0.f;
  ((float2*)out)[((size_t)w << 6) + lane] = make_float2(ax * sc, ay * sc);
}

// ============ fused SAGE conv: out = relu(A@Wl + bl + X@Wr) ============
// A: f32 (already mean). X: f32, or external dtype when xExt.
__global__ __launch_bounds__(256) void conv_fused(
    const float* __restrict__ A,
    const void* __restrict__ X, int xExt,
    const void* __restrict__ Wlv, const void* __restrict__ blv,
    const void* __restrict__ Wrv, int wrOff,
    float* __restrict__ out, int nrows, const int* __restrict__ flag) {
  int isb = *flag;
  __shared__ float sA[32][129];
  __shared__ float sX[32][129];
  int tid = threadIdx.x;
  int row0 = blockIdx.x * 32;

  const unsigned short* Wl_b = (const unsigned short*)Wlv;
  const float*          Wl_f = (const float*)Wlv;
  const unsigned short* Wr_b = (const unsigned short*)Wrv + wrOff;
  const float*          Wr_f = (const float*)Wrv + wrOff;

  for (int i = tid; i < 1024; i += 256) {
    int r = i >> 5, c4 = (i & 31) << 2;
    int gr = row0 + r;
    float4 v = make_float4(0.f, 0.f, 0.f, 0.f);
    if (gr < nrows) v = ((const float4*)(A + (((size_t)gr) << 7)))[i & 31];
    sA[r][c4 + 0] = v.x; sA[r][c4 + 1] = v.y; sA[r][c4 + 2] = v.z; sA[r][c4 + 3] = v.w;
  }
  for (int i = tid; i < 1024; i += 256) {
    int r = i >> 5, c4 = (i & 31) << 2;
    int gr = row0 + r;
    float4 v = make_float4(0.f, 0.f, 0.f, 0.f);
    if (gr < nrows) {
      if (xExt && isb) {
        uint2 u = *(const uint2*)((const unsigned short*)X + (((size_t)gr) << 7) + c4);
        v.x = __uint_as_float(u.x << 16); v.y = __uint_as_float(u.x & 0xFFFF0000u);
        v.z = __uint_as_float(u.y << 16); v.w = __uint_as_float(u.y & 0xFFFF0000u);
      } else {
        v = ((const float4*)X)[(((size_t)gr) << 5) + (i & 31)];
      }
    }
    sX[r][c4 + 0] = v.x; sX[r][c4 + 1] = v.y; sX[r][c4 + 2] = v.z; sX[r][c4 + 3] = v.w;
  }
  __syncthreads();

  int cg = tid & 15, rb = tid >> 4;
  float acc0[8], acc1[8];
#pragma unroll
  for (int j = 0; j < 8; ++j) { acc0[j] = 0.f; acc1[j] = 0.f; }

  if (isb) {
    for (int k = 0; k < 128; ++k) {
      float a0 = sA[rb][k], a1 = sA[rb + 16][k];
      float xv0 = sX[rb][k], xv1 = sX[rb + 16][k];
      uint4 ul = *(const uint4*)(Wl_b + (k << 7) + (cg << 3));
      uint4 ur = *(const uint4*)(Wr_b + (k << 7) + (cg << 3));
      float wl[8], wr[8];
      unpack8(ul, wl); unpack8(ur, wr);
#pragma unroll
      for (int j = 0; j < 8; ++j) {
        acc0[j] = fmaf(a0, wl[j], acc0[j]); acc0[j] = fmaf(xv0, wr[j], acc0[j]);
        acc1[j] = fmaf(a1, wl[j], acc1[j]); acc1[j] = fmaf(xv1, wr[j], acc1[j]);
      }
    }
  } else {
    for (int k = 0; k < 128; ++k) {
      float a0 = sA[rb][k], a1 = sA[rb + 16][k];
      float xv0 = sX[rb][k], xv1 = sX[rb + 16][k];
      const float* wlp = Wl_f + (k << 7) + (cg << 3);
      const float* wrp = Wr_f + (k << 7) + (cg << 3);
      float4 l0 = *(const float4*)wlp, l1 = *(const float4*)(wlp + 4);
      float4 r0 = *(const float4*)wrp, r1 = *(const float4*)(wrp + 4);
      float wl[8] = {l0.x, l0.y, l0.z, l0.w, l1.x, l1.y, l1.z, l1.w};
      float wr[8] = {r0.x, r0.y, r0.z, r0.w, r1.x, r1.y, r1.z, r1.w};
#pragma unroll
      for (int j = 0; j < 8; ++j) {
        acc0[j] = fmaf(a0, wl[j], acc0[j]); acc0[j] = fmaf(xv0, wr[j], acc0[j]);
        acc1[j] = fmaf(a1, wl[j], acc1[j]); acc1[j] = fmaf(xv1, wr[j], acc1[j]);
      }
    }
  }

  float bs[8];
  if (isb) {
    uint4 u = *(const uint4*)((const unsigned short*)blv + (cg << 3));
    unpack8(u, bs);
  } else {
    const float* bp = (const float*)blv + (cg << 3);
    float4 f0 = *(const float4*)bp, f1 = *(const float4*)(bp + 4);
    bs[0]=f0.x; bs[1]=f0.y; bs[2]=f0.z; bs[3]=f0.w; bs[4]=f1.x; bs[5]=f1.y; bs[6]=f1.z; bs[7]=f1.w;
  }
  int gr0 = row0 + rb;
  if (gr0 < nrows) {
    float* o = out + (((size_t)gr0) << 7) + (cg << 3);
    float4 o0, o1;
    o0.x = fmaxf(acc0[0] + bs[0], 0.f); o0.y = fmaxf(acc0[1] + bs[1], 0.f);
    o0.z = fmaxf(acc0[2] + bs[2], 0.f); o0.w = fmaxf(acc0[3] + bs[3], 0.f);
    o1.x = fmaxf(acc0[4] + bs[4], 0.f); o1.y = fmaxf(acc0[5] + bs[5], 0.f);
    o1.z = fmaxf(acc0[6] + bs[6], 0.f); o1.w = fmaxf(acc0[7] + bs[7], 0.f);
    *(float4*)o = o0; *(float4*)(o + 4) = o1;
  }
  int gr1 = row0 + rb + 16;
  if (gr1 < nrows) {
    float* o = out + (((size_t)gr1) << 7) + (cg << 3);
    float4 o0, o1;
    o0.x = fmaxf(acc1[0] + bs[0], 0.f); o0.y = fmaxf(acc1[1] + bs[1], 0.f);
    o0.z = fmaxf(acc1[2] + bs[2], 0.f); o0.w = fmaxf(acc1[3] + bs[3], 0.f);
    o1.x = fmaxf(acc1[4] + bs[4], 0.f); o1.y = fmaxf(acc1[5] + bs[5], 0.f);
    o1.z = fmaxf(acc1[6] + bs[6], 0.f); o1.w = fmaxf(acc1[7] + bs[7], 0.f);
    *(float4*)o = o0; *(float4*)(o + 4) = o1;
  }
}

// ============ sorted batch mean pool ============
__global__ void pool_batch(const float* __restrict__ hc2, const int* __restrict__ batch_c,
                           float* __restrict__ g, int nC) {
  int b = blockIdx.x, f = threadIdx.x; // 128 threads
  int lo = 0, hi = nC;
  while (lo < hi) { int m = (lo + hi) >> 1; if (batch_c[m] < b) lo = m + 1; else hi = m; }
  int st = lo;
  hi = nC;
  while (lo < hi) { int m = (lo + hi) >> 1; if (batch_c[m] < b + 1) lo = m + 1; else hi = m; }
  int en = lo;
  float acc = 0.f;
  for (int r = st; r < en; ++r) acc += hc2[((size_t)r << 7) + f];
  float sc = (en > st) ? 1.0f / (float)(en - st) : 0.f;
  g[b * 128 + f] = acc * sc;
}

__global__ void final_head(const float* __restrict__ g,
                           const void* __restrict__ W, const void* __restrict__ bias,
                           void* __restrict__ out, const int* __restrict__ flag) {
  int isb = *flag;
  int b = blockIdx.x, l = threadIdx.x;
  __shared__ float lg[16];
  if (l < NCLS) {
    float acc = isb ? bf2f(((const unsigned short*)bias)[l]) : ((const float*)bias)[l];
    for (int k = 0; k < NH; ++k) {
      float w = isb ? bf2f(((const unsigned short*)W)[k * NCLS + l]) : ((const float*)W)[k * NCLS + l];
      acc += g[b * NH + k] * w;
    }
    lg[l] = acc;
  }
  __syncthreads();
  if (l == 0) {
    float m = lg[0];
    for (int c = 1; c < NCLS; ++c) m = fmaxf(m, lg[c]);
    float se = 0.f;
    for (int c = 0; c < NCLS; ++c) se += expf(lg[c] - m);
    float lse = logf(se) + m;
    for (int c = 0; c < NCLS; ++c) {
      float o = lg[c] - lse;
      if (isb) ((__hip_bfloat16*)out)[b * NCLS + c] = __float2bfloat16(o);
      else     ((float*)out)[b * NCLS + c] = o;
    }
  }
}

// helper: build CSR for (src,dst) with n dst nodes, nE edges
static void build_csr(const int* src, const int* dst, int n, int nE,
                      int* rp, int* cur, int* colv, int* bsum, hipStream_t stream) {
  int nb = (n + SCAN_CHUNK - 1) / SCAN_CHUNK;
  hipMemsetAsync(cur, 0, (size_t)n * 4, stream);
  count_deg<<<(nE + 255) / 256, 256, 0, stream>>>(dst, cur, nE);
  scan_bsum<<<nb, 256, 0, stream>>>(cur, bsum, n);
  scan_top<<<1, 64, 0, stream>>>(bsum, nb);
  scan_write<<<nb, 256, 0, stream>>>(cur, bsum, rp, n, nE);
  copy_int<<<(n + 255) / 256, 256, 0, stream>>>(rp, cur, n);
  fill_csr<<<(nE + 255) / 256, 256, 0, stream>>>(src, dst, cur, colv, nE);
}

extern "C" void kernel_launch(void* const* d_in, const int* in_sizes, int n_in,
                              void* d_out, int out_size, void* d_ws, size_t ws_size,
                              hipStream_t stream) {
  (void)in_sizes; (void)n_in; (void)out_size; (void)ws_size;
  const void* x        = d_in[0];
  const int*  ei       = (const int*)d_in[1];
  const int*  src      = ei;
  const int*  dst      = ei + N_EDGES;
  const int*  ci       = (const int*)d_in[3];
  const int*  cn       = ci;              // cover: node ids (sources)
  const int*  cc       = ci + N_MEMB;     // cover: cluster ids (dests)
  const int*  eip      = (const int*)d_in[4];
  const int*  srcp     = eip;
  const int*  dstp     = eip + N_EDGESP;
  const int*  batch_c  = (const int*)d_in[5];
  const void* lin2_W   = d_in[6];
  const void* lin2_b   = d_in[7];
  const void* in_c1_Wl = d_in[8];  const void* in_c1_bl = d_in[9];  const void* in_c1_Wr = d_in[10];
  const void* in_c2_Wl = d_in[11]; const void* in_c2_bl = d_in[12]; const void* in_c2_Wr = d_in[13];
  const void* in_lin_W = d_in[14]; const void* in_lin_b = d_in[15];
  const void* b1_c1_Wl = d_in[16]; const void* b1_c1_bl = d_in[17]; const void* b1_c1_Wr = d_in[18];
  const void* b1_c2_Wl = d_in[19]; const void* b1_c2_bl = d_in[20]; const void* b1_c2_Wr = d_in[21];
  const void* b1_lin_W = d_in[22]; const void* b1_lin_b = d_in[23];

  float* ws   = (float*)d_ws;
  float* agg  = ws + O_AGG;
  float* x1b  = ws + O_X1;
  float* x2b  = ws + O_X2;
  int*   ib   = (int*)(ws + O_INT);
  int*   nrp  = ib + I_NRP;
  int*   ncur = ib + I_NCUR;
  int*   ncol = ib + I_NCOL;
  int*   crp  = ib + I_CRP;
  int*   ccur = ib + I_CCUR;
  int*   ccol = ib + I_CCOL;
  int*   mrp  = ib + I_MRP;
  int*   mcur = ib + I_MCUR;
  int*   mcol = ib + I_MCOL;
  int*   bsum = ib + I_BSUM;
  int*   flag = ib + I_FLAG;
  float* g    = ws + O_G;

  // buffer reuse
  float* h     = agg;                 // node block output
  float* hc    = x1b;                 // pooled cluster features
  float* aggc  = agg;                 // cluster conv1 agg
  float* xc1   = agg + 5120000;       // cluster conv1 out
  float* aggc2 = x2b;                 // cluster conv2 agg
  float* xc2   = x2b + 5120000;       // cluster conv2 out
  float* hc2   = x1b;                 // cluster block output

  probe_dtype<<<1, 64, 0, stream>>>((const unsigned short*)x, flag);

  // ---- CSR for node graph ----
  build_csr(src, dst, N_NODES, N_EDGES, nrp, ncur, ncol, bsum, stream);

  // ---- node block ----
  gather_mean_ext<<<(N_NODES + 3) / 4, 256, 0, stream>>>(x, nrp, ncol, agg, N_NODES, flag);
  conv_fused<<<N_NODES / 32, 256, 0, stream>>>(agg, x, 1, in_c1_Wl, in_c1_bl, in_c1_Wr, 0, x1b, N_NODES, flag);
  gather_mean_f32<<<(N_NODES + 3) / 4, 256, 0, stream>>>(x1b, nrp, ncol, agg, N_NODES);
  conv_fused<<<N_NODES / 32, 256, 0, stream>>>(agg, x1b, 0, in_c2_Wl, in_c2_bl, in_c2_Wr, 0, x2b, N_NODES, flag);
  conv_fused<<<N_NODES / 32, 256, 0, stream>>>(x1b, x2b, 0, in_lin_W, in_lin_b, in_lin_W, 16384, h, N_NODES, flag);

  // ---- cover pool: h -> hc (mean over memberships) ----
  build_csr(cn, cc, N_CLUST, N_MEMB, mrp, mcur, mcol, bsum, stream);
  gather_mean_f32<<<(N_CLUST + 3) / 4, 256, 0, stream>>>(h, mrp, mcol, hc, N_CLUST);

  // ---- CSR for cluster graph ----
  build_csr(srcp, dstp, N_CLUST, N_EDGESP, crp, ccur, ccol, bsum, stream);

  // ---- cluster block ----
  gather_mean_f32<<<(N_CLUST + 3) / 4, 256, 0, stream>>>(hc, crp, ccol, aggc, N_CLUST);
  conv_fused<<<N_CLUST / 32, 256, 0, stream>>>(aggc, hc, 0, b1_c1_Wl, b1_c1_bl, b1_c1_Wr, 0, xc1, N_CLUST, flag);
  gather_mean_f32<<<(N_CLUST + 3) / 4, 256, 0, stream>>>(xc1, crp, ccol, aggc2, N_CLUST);
  conv_fused<<<N_CLUST / 32, 256, 0, stream>>>(aggc2, xc1, 0, b1_c2_Wl, b1_c2_bl, b1_c2_Wr, 0, xc2, N_CLUST, flag);
  conv_fused<<<N_CLUST / 32, 256, 0, stream>>>(xc1, xc2, 0, b1_lin_W, b1_lin_b, b1_lin_W, 16384, hc2, N_CLUST, flag);

  // ---- global mean pool + head ----
  pool_batch<<<NB, 128, 0, stream>>>(hc2, batch_c, g, N_CLUST);
  final_head<<<NB, 64, 0, stream>>>(g, lin2_W, lin2_b, d_out, flag);
}

// Round 4
// 982.252 us; speedup vs baseline: 19.0497x; 1.8476x over previous
//
#include <hip/hip_runtime.h>
#include <hip/hip_bf16.h>

// ---- problem constants ----
#define N_NODES   100000
#define N_EDGES   1600000
#define N_MEMB    150000
#define N_CLUST   40000
#define N_EDGESP  800000
#define NB        64
#define NCLS      10

typedef __attribute__((ext_vector_type(4))) float f32x4;
typedef __attribute__((ext_vector_type(8))) short bf16x8;

// ---- workspace layout (byte offsets) ----
#define OFF_A0   0ul            // bf16 activation arena 0 (100000x128)
#define OFF_A1   25600000ul     // arena 1
#define OFF_A2   51200000ul     // arena 2
#define OFF_XB   76800000ul     // converted-input arena (bf16)
#define OFF_WP   102400000ul    // packed weights: 6 x 65536 B
#define OFF_WB   102793216ul    // converted biases + head weights (bf16)
#define OFF_IB   102801408ul    // int region
// int region offsets (ints)
#define I_NRP   0
#define I_NCUR  100004
#define I_NCOL  200008
#define I_CRP   1800008
#define I_CCUR  1840012
#define I_CCOL  1880012
#define I_MRP   2680012
#define I_MCUR  2720016
#define I_MCOL  2760016
#define I_BSUM  2910016
#define I_FLAG  2910072
#define I_END   2910080
// total ~114.5 MB (round 2 proved ws_size >= ~165 MB)

__device__ __forceinline__ unsigned short f2bf(float f) {   // RNE round
  unsigned u = __float_as_uint(f);
  return (unsigned short)((u + 0x7FFFu + ((u >> 16) & 1u)) >> 16);
}
__device__ __forceinline__ float bflo(unsigned u) { return __uint_as_float(u << 16); }
__device__ __forceinline__ float bfhi(unsigned u) { return __uint_as_float(u & 0xFFFF0000u); }

// Detect whether "float" inputs are bf16 (flag=1) or f32 (flag=0).
// bf16 N(0,1) data: even-index ushorts are real values, exponent <= ~0x82.
// f32 data: even-index ushorts are mantissa halves -> ~48% have e > 0x85.
__global__ void probe_dtype(const unsigned short* __restrict__ x, int* __restrict__ flag) {
  if (blockIdx.x != 0 || threadIdx.x != 0) return;
  int wild = 0;
  for (int i = 0; i < 1024; i += 2) {
    int e = (x[i] >> 7) & 0xFF;
    if (e > 0x85) wild++;
  }
  *flag = (wild < 8) ? 1 : 0;
}

// convert external x (f32 or bf16 per flag) -> bf16 arena; 8 elts/thread
__global__ __launch_bounds__(256) void cvt_x(const void* __restrict__ x, uint4* __restrict__ xB,
                                             const int* __restrict__ flag) {
  int gid = blockIdx.x * 256 + threadIdx.x;
  if (gid >= 1600000) return;
  if (*flag) {
    xB[gid] = ((const uint4*)x)[gid];
  } else {
    const float4* xf = (const float4*)x;
    float4 a = xf[2 * gid], b = xf[2 * gid + 1];
    unsigned short v[8] __attribute__((aligned(16)));
    v[0] = f2bf(a.x); v[1] = f2bf(a.y); v[2] = f2bf(a.z); v[3] = f2bf(a.w);
    v[4] = f2bf(b.x); v[5] = f2bf(b.y); v[6] = f2bf(b.z); v[7] = f2bf(b.w);
    xB[gid] = *(const uint4*)v;
  }
}

// convert 6 bias vecs (128) + lin2_W (1280) + lin2_b (10) -> bf16 block
__global__ void cvt_small(const void* b0, const void* b1, const void* b2,
                          const void* b3, const void* b4, const void* b5,
                          const void* w2, const void* bb2,
                          unsigned short* __restrict__ dst, const int* __restrict__ flag) {
  int isb = *flag;
  int gid = blockIdx.x * 256 + threadIdx.x;
  const void* src; int local;
  if (gid < 768) {
    int seg = gid >> 7; local = gid & 127;
    src = (seg == 0) ? b0 : (seg == 1) ? b1 : (seg == 2) ? b2 : (seg == 3) ? b3 : (seg == 4) ? b4 : b5;
  } else if (gid < 2048) { src = w2;  local = gid - 768; }
  else if (gid < 2058)   { src = bb2; local = gid - 2048; }
  else return;
  dst[gid] = isb ? ((const unsigned short*)src)[local] : f2bf(((const float*)src)[local]);
}

// ============ CSR build (verified round 2) ============
__global__ __launch_bounds__(256) void count_deg(const int* __restrict__ dstI, int* __restrict__ deg, int nE) {
  int t = blockIdx.x * 256 + threadIdx.x;
  if (t < nE) atomicAdd(&deg[dstI[t]], 1);
}

#define SCAN_CHUNK 2048
__global__ __launch_bounds__(256) void scan_bsum(const int* __restrict__ v, int* __restrict__ bsum, int n) {
  __shared__ int sw[4];
  int tid = threadIdx.x;
  int base = blockIdx.x * SCAN_CHUNK + tid * 8;
  int s = 0;
#pragma unroll
  for (int j = 0; j < 8; ++j) { int i = base + j; s += (i < n) ? v[i] : 0; }
  for (int off = 32; off; off >>= 1) s += __shfl_down(s, off);
  if ((tid & 63) == 0) sw[tid >> 6] = s;
  __syncthreads();
  if (tid == 0) bsum[blockIdx.x] = sw[0] + sw[1] + sw[2] + sw[3];
}

__global__ void scan_top(int* __restrict__ bsum, int nb) {
  int lane = threadIdx.x;
  int v = (lane < nb) ? bsum[lane] : 0;
  int inc = v;
  for (int off = 1; off < 64; off <<= 1) {
    int u = __shfl_up(inc, off);
    if (lane >= off) inc += u;
  }
  if (lane < nb) bsum[lane] = inc - v;
}

__global__ __launch_bounds__(256) void scan_write(const int* __restrict__ v, const int* __restrict__ bsum,
                                                  int* __restrict__ rowptr, int n, int total) {
  __shared__ int sw[4];
  int tid = threadIdx.x, lane = tid & 63, wv = tid >> 6;
  int base = blockIdx.x * SCAN_CHUNK + tid * 8;
  int x[8]; int s = 0;
#pragma unroll
  for (int j = 0; j < 8; ++j) { int i = base + j; int t = (i < n) ? v[i] : 0; x[j] = s; s += t; }
  int inc = s;
  for (int off = 1; off < 64; off <<= 1) {
    int u = __shfl_up(inc, off);
    if (lane >= off) inc += u;
  }
  int wexcl = inc - s;
  if (lane == 63) sw[wv] = inc;
  __syncthreads();
  int woff = 0;
  for (int k = 0; k < wv; ++k) woff += sw[k];
  int off0 = bsum[blockIdx.x] + woff + wexcl;
#pragma unroll
  for (int j = 0; j < 8; ++j) { int i = base + j; if (i < n) rowptr[i] = off0 + x[j]; }
  if (blockIdx.x == 0 && tid == 0) rowptr[n] = total;
}

__global__ __launch_bounds__(256) void copy_int(const int* __restrict__ a, int* __restrict__ b, int n) {
  int t = blockIdx.x * 256 + threadIdx.x;
  if (t < n) b[t] = a[t];
}

__global__ __launch_bounds__(256) void fill_csr(const int* __restrict__ srcI, const int* __restrict__ dstI,
                                                int* __restrict__ cur, int* __restrict__ col, int nE) {
  int t = blockIdx.x * 256 + threadIdx.x;
  if (t < nE) { int p = atomicAdd(&cur[dstI[t]], 1); col[p] = srcI[t]; }
}

// ============ pull-mode mean aggregation, bf16 rows (256 B) ============
__global__ __launch_bounds__(256) void gather_mean_bf16(
    const unsigned* __restrict__ x, const int* __restrict__ rowptr, const int* __restrict__ col,
    unsigned* __restrict__ out, int n) {
  int w = (blockIdx.x * 256 + threadIdx.x) >> 6;
  if (w >= n) return;
  int lane = threadIdx.x & 63;
  int s0 = rowptr[w], s1 = rowptr[w + 1];
  float ax = 0.f, ay = 0.f, bx = 0.f, by = 0.f;
  int j = s0;
  for (; j + 1 < s1; j += 2) {
    unsigned uA = x[((size_t)col[j]     << 6) + lane];
    unsigned uB = x[((size_t)col[j + 1] << 6) + lane];
    ax += bflo(uA); ay += bfhi(uA);
    bx += bflo(uB); by += bfhi(uB);
  }
  if (j < s1) {
    unsigned uA = x[((size_t)col[j] << 6) + lane];
    ax += bflo(uA); ay += bfhi(uA);
  }
  float sc = (s1 > s0) ? 1.0f / (float)(s1 - s0) : 0.f;
  unsigned r = (unsigned)f2bf((ax + bx) * sc) | ((unsigned)f2bf((ay + by) * sc) << 16);
  out[((size_t)w << 6) + lane] = r;
}

// ============ weight pre-pack into MFMA A-fragment order ============
// dst[(ks*8+mt)*64+lane] = 8 bf16: W[32ks+8*(lane>>4)+j][16mt+(lane&15)];
// row k from Wl (k<128) else Wr (k-128). Wr = Wrv advanced wrOff ELEMENTS.
__global__ __launch_bounds__(256) void pack_w(const void* __restrict__ Wlv, const void* __restrict__ Wrv,
                                              int wrOff, uint4* __restrict__ dst,
                                              const int* __restrict__ flag) {
  int isb = *flag;
  int t = blockIdx.x * 256 + threadIdx.x;      // 16 blocks x 256 = 4096
  int lane = t & 63, mt = (t >> 6) & 7, ks = t >> 9;
  int feat = mt * 16 + (lane & 15);
  int k0 = ks * 32 + (lane >> 4) * 8;
  unsigned short v[8] __attribute__((aligned(16)));
#pragma unroll
  for (int j = 0; j < 8; ++j) {
    int k = k0 + j;
    int idx = ((k < 128) ? k * 128 : (k - 128) * 128 + wrOff) + feat;
    const void* W = (k < 128) ? Wlv : Wrv;
    v[j] = isb ? ((const unsigned short*)W)[idx] : f2bf(((const float*)W)[idx]);
  }
  dst[t] = *(const uint4*)v;
}

// ============ MFMA conv: out = relu([A|X] @ [Wl;Wr] + b), K=256 ============
// 64 rows/block, 4 waves; wave w owns rows 16w..16w+15, all 128 out features.
// Operand swap: A=W^T (packed), B=Act^T (LDS) -> lane stores 4 consecutive
// features of one row. LDS: 64 rows x 512 B, XOR-16B swizzle (addr^=(row&7)<<4).
__global__ __launch_bounds__(256) void conv_mfma(
    const unsigned short* __restrict__ Abuf, const unsigned short* __restrict__ Xbuf,
    const uint4* __restrict__ Wp, const unsigned short* __restrict__ bias,
    unsigned short* __restrict__ out, int nrows) {
  __shared__ uint4 lds[2048];                  // 32 KB
  int tid = threadIdx.x;
  int row0 = blockIdx.x * 64;

  const char* Ab = (const char*)Abuf;
  const char* Xb = (const char*)Xbuf;
  for (int c = tid; c < 2048; c += 256) {
    int r = c >> 5, seg = c & 31;
    int gr = row0 + r;
    uint4 v = make_uint4(0u, 0u, 0u, 0u);
    if (gr < nrows) {
      const char* srcp = (seg < 16) ? (Ab + (size_t)gr * 256 + seg * 16)
                                    : (Xb + (size_t)gr * 256 + (seg - 16) * 16);
      v = *(const uint4*)srcp;
    }
    int byteoff = (r << 9) + ((seg << 4) ^ ((r & 7) << 4));
    *(uint4*)((char*)lds + byteoff) = v;
  }
  __syncthreads();

  int lane = tid & 63, w = tid >> 6;
  int brow = 16 * w + (lane & 15);
  int q = lane >> 4;
  int q16 = q << 4;

  f32x4 acc[8];
#pragma unroll
  for (int mt = 0; mt < 8; ++mt) acc[mt] = (f32x4){0.f, 0.f, 0.f, 0.f};

  const uint4* wp_lane = Wp + lane;
  int bbase = brow << 9;
  int bxor = (brow & 7) << 4;

  for (int ks = 0; ks < 8; ++ks) {
    int koff = ks * 64 + q16;
    uint4 bv = *(const uint4*)((const char*)lds + bbase + (koff ^ bxor));
    bf16x8 bfrag = __builtin_bit_cast(bf16x8, bv);
#pragma unroll
    for (int mt = 0; mt < 8; ++mt) {
      uint4 av = wp_lane[(ks * 8 + mt) * 64];
      bf16x8 afrag = __builtin_bit_cast(bf16x8, av);
      acc[mt] = __builtin_amdgcn_mfma_f32_16x16x32_bf16(afrag, bfrag, acc[mt], 0, 0, 0);
    }
  }

  int orow = row0 + brow;
  if (orow < nrows) {
    unsigned short* op = out + (size_t)orow * 128;
#pragma unroll
    for (int mt = 0; mt < 8; ++mt) {
      int f0 = mt * 16 + q * 4;
      unsigned b01 = *(const unsigned*)(bias + f0);
      unsigned b23 = *(const unsigned*)(bias + f0 + 2);
      float v0 = fmaxf(acc[mt][0] + bflo(b01), 0.f);
      float v1 = fmaxf(acc[mt][1] + bfhi(b01), 0.f);
      float v2 = fmaxf(acc[mt][2] + bflo(b23), 0.f);
      float v3 = fmaxf(acc[mt][3] + bfhi(b23), 0.f);
      uint2 pk;
      pk.x = (unsigned)f2bf(v0) | ((unsigned)f2bf(v1) << 16);
      pk.y = (unsigned)f2bf(v2) | ((unsigned)f2bf(v3) << 16);
      *(uint2*)(op + f0) = pk;
    }
  }
}

// ============ sorted-batch mean pool (bf16 in, f32 out) ============
__global__ void pool_batch(const unsigned short* __restrict__ hc2, const int* __restrict__ batch_c,
                           float* __restrict__ g, int nC) {
  int b = blockIdx.x, f = threadIdx.x;         // 128 threads
  int lo = 0, hi = nC;
  while (lo < hi) { int m = (lo + hi) >> 1; if (batch_c[m] < b) lo = m + 1; else hi = m; }
  int st = lo;
  hi = nC;
  while (lo < hi) { int m = (lo + hi) >> 1; if (batch_c[m] < b + 1) lo = m + 1; else hi = m; }
  int en = lo;
  float acc = 0.f;
  for (int r = st; r < en; ++r) acc += bflo((unsigned)hc2[((size_t)r << 7) + f]);
  float sc = (en > st) ? 1.0f / (float)(en - st) : 0.f;
  g[b * 128 + f] = acc * sc;
}

__global__ void final_head(const float* __restrict__ g, const unsigned short* __restrict__ WB,
                           void* __restrict__ out, const int* __restrict__ flag) {
  int isb = *flag;
  const unsigned short* W    = WB + 768;       // [128][10] bf16
  const unsigned short* bias = WB + 2048;      // [10] bf16
  int b = blockIdx.x, l = threadIdx.x;
  __shared__ float lg[16];
  if (l < NCLS) {
    float acc = bflo((unsigned)bias[l]);
    for (int k = 0; k < 128; ++k)
      acc += g[b * 128 + k] * bflo((unsigned)W[k * NCLS + l]);
    lg[l] = acc;
  }
  __syncthreads();
  if (l == 0) {
    float m = lg[0];
    for (int c = 1; c < NCLS; ++c) m = fmaxf(m, lg[c]);
    float se = 0.f;
    for (int c = 0; c < NCLS; ++c) se += expf(lg[c] - m);
    float lse = logf(se) + m;
    for (int c = 0; c < NCLS; ++c) {
      float o = lg[c] - lse;
      if (isb) ((unsigned short*)out)[b * NCLS + c] = f2bf(o);
      else     ((float*)out)[b * NCLS + c] = o;
    }
  }
}

static void build_csr(const int* src, const int* dst, int n, int nE,
                      int* rp, int* cur, int* colv, int* bsum, hipStream_t stream) {
  int nb = (n + SCAN_CHUNK - 1) / SCAN_CHUNK;
  hipMemsetAsync(cur, 0, (size_t)n * 4, stream);
  count_deg<<<(nE + 255) / 256, 256, 0, stream>>>(dst, cur, nE);
  scan_bsum<<<nb, 256, 0, stream>>>(cur, bsum, n);
  scan_top<<<1, 64, 0, stream>>>(bsum, nb);
  scan_write<<<nb, 256, 0, stream>>>(cur, bsum, rp, n, nE);
  copy_int<<<(n + 255) / 256, 256, 0, stream>>>(rp, cur, n);
  fill_csr<<<(nE + 255) / 256, 256, 0, stream>>>(src, dst, cur, colv, nE);
}

extern "C" void kernel_launch(void* const* d_in, const int* in_sizes, int n_in,
                              void* d_out, int out_size, void* d_ws, size_t ws_size,
                              hipStream_t stream) {
  (void)in_sizes; (void)n_in; (void)out_size; (void)ws_size;
  const void* x        = d_in[0];
  const int*  ei       = (const int*)d_in[1];
  const int*  src      = ei;
  const int*  dst      = ei + N_EDGES;
  const int*  ci       = (const int*)d_in[3];
  const int*  cn       = ci;                // cover: node ids (sources)
  const int*  cc       = ci + N_MEMB;       // cover: cluster ids (dests)
  const int*  eip      = (const int*)d_in[4];
  const int*  srcp     = eip;
  const int*  dstp     = eip + N_EDGESP;
  const int*  batch_c  = (const int*)d_in[5];
  const void* lin2_W   = d_in[6];
  const void* lin2_b   = d_in[7];
  const void* in_c1_Wl = d_in[8];  const void* in_c1_bl = d_in[9];  const void* in_c1_Wr = d_in[10];
  const void* in_c2_Wl = d_in[11]; const void* in_c2_bl = d_in[12]; const void* in_c2_Wr = d_in[13];
  const void* in_lin_W = d_in[14]; const void* in_lin_b = d_in[15];
  const void* b1_c1_Wl = d_in[16]; const void* b1_c1_bl = d_in[17]; const void* b1_c1_Wr = d_in[18];
  const void* b1_c2_Wl = d_in[19]; const void* b1_c2_bl = d_in[20]; const void* b1_c2_Wr = d_in[21];
  const void* b1_lin_W = d_in[22]; const void* b1_lin_b = d_in[23];

  char* base = (char*)d_ws;
  unsigned short* A0 = (unsigned short*)(base + OFF_A0);
  unsigned short* A1 = (unsigned short*)(base + OFF_A1);
  unsigned short* A2 = (unsigned short*)(base + OFF_A2);
  unsigned short* xB = (unsigned short*)(base + OFF_XB);
  uint4* wp0 = (uint4*)(base + OFF_WP);
  unsigned short* WBp = (unsigned short*)(base + OFF_WB);
  int*   ib  = (int*)(base + OFF_IB);
  int *nrp = ib + I_NRP, *ncur = ib + I_NCUR, *ncol = ib + I_NCOL;
  int *crp = ib + I_CRP, *ccur = ib + I_CCUR, *ccol = ib + I_CCOL;
  int *mrp = ib + I_MRP, *mcur = ib + I_MCUR, *mcol = ib + I_MCOL;
  int *bsum = ib + I_BSUM;
  int *flag = ib + I_FLAG;
  float* g = (float*)(ib + I_END);

#define WPK(L) (wp0 + (L) * 4096)

  probe_dtype<<<1, 64, 0, stream>>>((const unsigned short*)x, flag);

  // ---- dtype-generic ingestion: everything -> bf16 ----
  cvt_x<<<6250, 256, 0, stream>>>(x, (uint4*)xB, flag);
  pack_w<<<16, 256, 0, stream>>>(in_c1_Wl, in_c1_Wr, 0,     WPK(0), flag);
  pack_w<<<16, 256, 0, stream>>>(in_c2_Wl, in_c2_Wr, 0,     WPK(1), flag);
  pack_w<<<16, 256, 0, stream>>>(in_lin_W, in_lin_W, 16384, WPK(2), flag);
  pack_w<<<16, 256, 0, stream>>>(b1_c1_Wl, b1_c1_Wr, 0,     WPK(3), flag);
  pack_w<<<16, 256, 0, stream>>>(b1_c2_Wl, b1_c2_Wr, 0,     WPK(4), flag);
  pack_w<<<16, 256, 0, stream>>>(b1_lin_W, b1_lin_W, 16384, WPK(5), flag);
  cvt_small<<<9, 256, 0, stream>>>(in_c1_bl, in_c2_bl, in_lin_b,
                                   b1_c1_bl, b1_c2_bl, b1_lin_b,
                                   lin2_W, lin2_b, WBp, flag);

  // ---- CSRs ----
  build_csr(src,  dst,  N_NODES, N_EDGES,  nrp, ncur, ncol, bsum, stream);
  build_csr(cn,   cc,   N_CLUST, N_MEMB,   mrp, mcur, mcol, bsum, stream);
  build_csr(srcp, dstp, N_CLUST, N_EDGESP, crp, ccur, ccol, bsum, stream);

  int gN = (N_NODES + 63) / 64, gC = (N_CLUST + 63) / 64;

  // ---- node block ----
  gather_mean_bf16<<<N_NODES / 4, 256, 0, stream>>>((const unsigned*)xB, nrp, ncol, (unsigned*)A0, N_NODES);
  conv_mfma<<<gN, 256, 0, stream>>>(A0, xB, WPK(0), WBp + 0,   A1, N_NODES);
  gather_mean_bf16<<<N_NODES / 4, 256, 0, stream>>>((const unsigned*)A1, nrp, ncol, (unsigned*)A0, N_NODES);
  conv_mfma<<<gN, 256, 0, stream>>>(A0, A1, WPK(1), WBp + 128, A2, N_NODES);
  conv_mfma<<<gN, 256, 0, stream>>>(A1, A2, WPK(2), WBp + 256, A0, N_NODES);     // h -> A0

  // ---- cover pool: h -> hc (A1) ----
  gather_mean_bf16<<<N_CLUST / 4, 256, 0, stream>>>((const unsigned*)A0, mrp, mcol, (unsigned*)A1, N_CLUST);

  // ---- cluster block ----
  gather_mean_bf16<<<N_CLUST / 4, 256, 0, stream>>>((const unsigned*)A1, crp, ccol, (unsigned*)A2, N_CLUST);
  conv_mfma<<<gC, 256, 0, stream>>>(A2, A1, WPK(3), WBp + 384, A0, N_CLUST);     // xc1 -> A0
  gather_mean_bf16<<<N_CLUST / 4, 256, 0, stream>>>((const unsigned*)A0, crp, ccol, (unsigned*)A2, N_CLUST);
  conv_mfma<<<gC, 256, 0, stream>>>(A2, A0, WPK(4), WBp + 512, A1, N_CLUST);     // xc2 -> A1
  conv_mfma<<<gC, 256, 0, stream>>>(A0, A1, WPK(5), WBp + 640, A2, N_CLUST);     // hc2 -> A2

  // ---- global mean pool + head ----
  pool_batch<<<NB, 128, 0, stream>>>(A2, batch_c, g, N_CLUST);
  final_head<<<NB, 64, 0, stream>>>(g, WBp, d_out, flag);
}

// Round 5
// 755.577 us; speedup vs baseline: 24.7646x; 1.3000x over previous
//
#include <hip/hip_runtime.h>
#include <hip/hip_bf16.h>

// ---- problem constants ----
#define N_NODES   100000
#define N_EDGES   1600000
#define N_MEMB    150000
#define N_CLUST   40000
#define N_EDGESP  800000
#define NB        64
#define NCLS      10

typedef __attribute__((ext_vector_type(4))) float f32x4;
typedef __attribute__((ext_vector_type(8))) short bf16x8;

// ---- workspace layout (byte offsets) ----
#define OFF_A0   0ul            // bf16 activation arena 0 (100000x128)
#define OFF_A1   25600000ul     // arena 1
#define OFF_A2   51200000ul     // arena 2
#define OFF_XB   76800000ul     // converted-input arena (bf16)
#define OFF_WP   102400000ul    // packed weights: 6 x 65536 B
#define OFF_WB   102793216ul    // converted biases + head weights (bf16)
#define OFF_IB   102801408ul    // int region
// int region offsets (ints)
#define I_NRP   0
#define I_NCUR  100004
#define I_NCOL  200008
#define I_CRP   1800008
#define I_CCUR  1840012
#define I_CCOL  1880012
#define I_MRP   2680012
#define I_MCUR  2720016
#define I_MCOL  2760016
#define I_BSUM  2910016
#define I_FLAG  2910072
#define I_END   2910080

__device__ __forceinline__ unsigned short f2bf(float f) {   // RNE round
  unsigned u = __float_as_uint(f);
  return (unsigned short)((u + 0x7FFFu + ((u >> 16) & 1u)) >> 16);
}
__device__ __forceinline__ float bflo(unsigned u) { return __uint_as_float(u << 16); }
__device__ __forceinline__ float bfhi(unsigned u) { return __uint_as_float(u & 0xFFFF0000u); }

// Detect whether "float" inputs are bf16 (flag=1) or f32 (flag=0).
__global__ void probe_dtype(const unsigned short* __restrict__ x, int* __restrict__ flag) {
  if (blockIdx.x != 0 || threadIdx.x != 0) return;
  int wild = 0;
  for (int i = 0; i < 1024; i += 2) {
    int e = (x[i] >> 7) & 0xFF;
    if (e > 0x85) wild++;
  }
  *flag = (wild < 8) ? 1 : 0;
}

// convert external x (f32 or bf16 per flag) -> bf16 arena; 8 elts/thread
__global__ __launch_bounds__(256) void cvt_x(const void* __restrict__ x, uint4* __restrict__ xB,
                                             const int* __restrict__ flag) {
  int gid = blockIdx.x * 256 + threadIdx.x;
  if (gid >= 1600000) return;
  if (*flag) {
    xB[gid] = ((const uint4*)x)[gid];
  } else {
    const float4* xf = (const float4*)x;
    float4 a = xf[2 * gid], b = xf[2 * gid + 1];
    unsigned short v[8] __attribute__((aligned(16)));
    v[0] = f2bf(a.x); v[1] = f2bf(a.y); v[2] = f2bf(a.z); v[3] = f2bf(a.w);
    v[4] = f2bf(b.x); v[5] = f2bf(b.y); v[6] = f2bf(b.z); v[7] = f2bf(b.w);
    xB[gid] = *(const uint4*)v;
  }
}

// convert 6 bias vecs (128) + lin2_W (1280) + lin2_b (10) -> bf16 block
__global__ void cvt_small(const void* b0, const void* b1, const void* b2,
                          const void* b3, const void* b4, const void* b5,
                          const void* w2, const void* bb2,
                          unsigned short* __restrict__ dst, const int* __restrict__ flag) {
  int isb = *flag;
  int gid = blockIdx.x * 256 + threadIdx.x;
  const void* src; int local;
  if (gid < 768) {
    int seg = gid >> 7; local = gid & 127;
    src = (seg == 0) ? b0 : (seg == 1) ? b1 : (seg == 2) ? b2 : (seg == 3) ? b3 : (seg == 4) ? b4 : b5;
  } else if (gid < 2048) { src = w2;  local = gid - 768; }
  else if (gid < 2058)   { src = bb2; local = gid - 2048; }
  else return;
  dst[gid] = isb ? ((const unsigned short*)src)[local] : f2bf(((const float*)src)[local]);
}

// ============ CSR build (verified) ============
__global__ __launch_bounds__(256) void count_deg(const int* __restrict__ dstI, int* __restrict__ deg, int nE) {
  int t = blockIdx.x * 256 + threadIdx.x;
  if (t < nE) atomicAdd(&deg[dstI[t]], 1);
}

#define SCAN_CHUNK 2048
__global__ __launch_bounds__(256) void scan_bsum(const int* __restrict__ v, int* __restrict__ bsum, int n) {
  __shared__ int sw[4];
  int tid = threadIdx.x;
  int base = blockIdx.x * SCAN_CHUNK + tid * 8;
  int s = 0;
#pragma unroll
  for (int j = 0; j < 8; ++j) { int i = base + j; s += (i < n) ? v[i] : 0; }
  for (int off = 32; off; off >>= 1) s += __shfl_down(s, off);
  if ((tid & 63) == 0) sw[tid >> 6] = s;
  __syncthreads();
  if (tid == 0) bsum[blockIdx.x] = sw[0] + sw[1] + sw[2] + sw[3];
}

__global__ void scan_top(int* __restrict__ bsum, int nb) {
  int lane = threadIdx.x;
  int v = (lane < nb) ? bsum[lane] : 0;
  int inc = v;
  for (int off = 1; off < 64; off <<= 1) {
    int u = __shfl_up(inc, off);
    if (lane >= off) inc += u;
  }
  if (lane < nb) bsum[lane] = inc - v;
}

__global__ __launch_bounds__(256) void scan_write(const int* __restrict__ v, const int* __restrict__ bsum,
                                                  int* __restrict__ rowptr, int n, int total) {
  __shared__ int sw[4];
  int tid = threadIdx.x, lane = tid & 63, wv = tid >> 6;
  int base = blockIdx.x * SCAN_CHUNK + tid * 8;
  int x[8]; int s = 0;
#pragma unroll
  for (int j = 0; j < 8; ++j) { int i = base + j; int t = (i < n) ? v[i] : 0; x[j] = s; s += t; }
  int inc = s;
  for (int off = 1; off < 64; off <<= 1) {
    int u = __shfl_up(inc, off);
    if (lane >= off) inc += u;
  }
  int wexcl = inc - s;
  if (lane == 63) sw[wv] = inc;
  __syncthreads();
  int woff = 0;
  for (int k = 0; k < wv; ++k) woff += sw[k];
  int off0 = bsum[blockIdx.x] + woff + wexcl;
#pragma unroll
  for (int j = 0; j < 8; ++j) { int i = base + j; if (i < n) rowptr[i] = off0 + x[j]; }
  if (blockIdx.x == 0 && tid == 0) rowptr[n] = total;
}

__global__ __launch_bounds__(256) void copy_int(const int* __restrict__ a, int* __restrict__ b, int n) {
  int t = blockIdx.x * 256 + threadIdx.x;
  if (t < n) b[t] = a[t];
}

__global__ __launch_bounds__(256) void fill_csr(const int* __restrict__ srcI, const int* __restrict__ dstI,
                                                int* __restrict__ cur, int* __restrict__ col, int nE) {
  int t = blockIdx.x * 256 + threadIdx.x;
  if (t < nE) { int p = atomicAdd(&cur[dstI[t]], 1); col[p] = srcI[t]; }
}

// ============ pull-mode mean aggregation, bf16 rows (256 B) ============
// one wave per dst row; lane owns 2 features; 4-deep unroll for MLP latency
__global__ __launch_bounds__(256) void gather_mean_bf16(
    const unsigned* __restrict__ x, const int* __restrict__ rowptr, const int* __restrict__ col,
    unsigned* __restrict__ out, int n) {
  int w = (blockIdx.x * 256 + threadIdx.x) >> 6;
  if (w >= n) return;
  int lane = threadIdx.x & 63;
  int s0 = rowptr[w], s1 = rowptr[w + 1];
  float ax = 0.f, ay = 0.f;
  int j = s0;
  for (; j + 3 < s1; j += 4) {
    int c0 = col[j], c1 = col[j + 1], c2 = col[j + 2], c3 = col[j + 3];
    unsigned u0 = x[((size_t)c0 << 6) + lane];
    unsigned u1 = x[((size_t)c1 << 6) + lane];
    unsigned u2 = x[((size_t)c2 << 6) + lane];
    unsigned u3 = x[((size_t)c3 << 6) + lane];
    ax += bflo(u0) + bflo(u1) + bflo(u2) + bflo(u3);
    ay += bfhi(u0) + bfhi(u1) + bfhi(u2) + bfhi(u3);
  }
  for (; j < s1; ++j) {
    unsigned u = x[((size_t)col[j] << 6) + lane];
    ax += bflo(u); ay += bfhi(u);
  }
  float sc = (s1 > s0) ? 1.0f / (float)(s1 - s0) : 0.f;
  unsigned r = (unsigned)f2bf(ax * sc) | ((unsigned)f2bf(ay * sc) << 16);
  out[((size_t)w << 6) + lane] = r;
}

// ============ weight pre-pack into MFMA A-fragment order ============
__global__ __launch_bounds__(256) void pack_w(const void* __restrict__ Wlv, const void* __restrict__ Wrv,
                                              int wrOff, uint4* __restrict__ dst,
                                              const int* __restrict__ flag) {
  int isb = *flag;
  int t = blockIdx.x * 256 + threadIdx.x;      // 16 blocks x 256 = 4096
  int lane = t & 63, mt = (t >> 6) & 7, ks = t >> 9;
  int feat = mt * 16 + (lane & 15);
  int k0 = ks * 32 + (lane >> 4) * 8;
  unsigned short v[8] __attribute__((aligned(16)));
#pragma unroll
  for (int j = 0; j < 8; ++j) {
    int k = k0 + j;
    int idx = ((k < 128) ? k * 128 : (k - 128) * 128 + wrOff) + feat;
    const void* W = (k < 128) ? Wlv : Wrv;
    v[j] = isb ? ((const unsigned short*)W)[idx] : f2bf(((const float*)W)[idx]);
  }
  dst[t] = *(const uint4*)v;
}

// ============ MFMA conv: out = relu([A|X] @ [Wl;Wr] + b), K=256 ============
__global__ __launch_bounds__(256) void conv_mfma(
    const unsigned short* __restrict__ Abuf, const unsigned short* __restrict__ Xbuf,
    const uint4* __restrict__ Wp, const unsigned short* __restrict__ bias,
    unsigned short* __restrict__ out, int nrows) {
  __shared__ uint4 lds[2048];                  // 32 KB
  int tid = threadIdx.x;
  int row0 = blockIdx.x * 64;

  const char* Ab = (const char*)Abuf;
  const char* Xb = (const char*)Xbuf;
  for (int c = tid; c < 2048; c += 256) {
    int r = c >> 5, seg = c & 31;
    int gr = row0 + r;
    uint4 v = make_uint4(0u, 0u, 0u, 0u);
    if (gr < nrows) {
      const char* srcp = (seg < 16) ? (Ab + (size_t)gr * 256 + seg * 16)
                                    : (Xb + (size_t)gr * 256 + (seg - 16) * 16);
      v = *(const uint4*)srcp;
    }
    int byteoff = (r << 9) + ((seg << 4) ^ ((r & 7) << 4));
    *(uint4*)((char*)lds + byteoff) = v;
  }
  __syncthreads();

  int lane = tid & 63, w = tid >> 6;
  int brow = 16 * w + (lane & 15);
  int q = lane >> 4;
  int q16 = q << 4;

  f32x4 acc[8];
#pragma unroll
  for (int mt = 0; mt < 8; ++mt) acc[mt] = (f32x4){0.f, 0.f, 0.f, 0.f};

  const uint4* wp_lane = Wp + lane;
  int bbase = brow << 9;
  int bxor = (brow & 7) << 4;

  for (int ks = 0; ks < 8; ++ks) {
    int koff = ks * 64 + q16;
    uint4 bv = *(const uint4*)((const char*)lds + bbase + (koff ^ bxor));
    bf16x8 bfrag = __builtin_bit_cast(bf16x8, bv);
#pragma unroll
    for (int mt = 0; mt < 8; ++mt) {
      uint4 av = wp_lane[(ks * 8 + mt) * 64];
      bf16x8 afrag = __builtin_bit_cast(bf16x8, av);
      acc[mt] = __builtin_amdgcn_mfma_f32_16x16x32_bf16(afrag, bfrag, acc[mt], 0, 0, 0);
    }
  }

  int orow = row0 + brow;
  if (orow < nrows) {
    unsigned short* op = out + (size_t)orow * 128;
#pragma unroll
    for (int mt = 0; mt < 8; ++mt) {
      int f0 = mt * 16 + q * 4;
      unsigned b01 = *(const unsigned*)(bias + f0);
      unsigned b23 = *(const unsigned*)(bias + f0 + 2);
      float v0 = fmaxf(acc[mt][0] + bflo(b01), 0.f);
      float v1 = fmaxf(acc[mt][1] + bfhi(b01), 0.f);
      float v2 = fmaxf(acc[mt][2] + bflo(b23), 0.f);
      float v3 = fmaxf(acc[mt][3] + bfhi(b23), 0.f);
      uint2 pk;
      pk.x = (unsigned)f2bf(v0) | ((unsigned)f2bf(v1) << 16);
      pk.y = (unsigned)f2bf(v2) | ((unsigned)f2bf(v3) << 16);
      *(uint2*)(op + f0) = pk;
    }
  }
}

// ============ fused batch mean pool + head (per-graph block) ============
// 512 threads = 8 waves; waves stride rows, lane owns 2 features.
__global__ __launch_bounds__(512) void pool_head(
    const unsigned* __restrict__ hc2, const int* __restrict__ batch_c,
    const unsigned short* __restrict__ WB, void* __restrict__ out,
    const int* __restrict__ flag, int nC) {
  int b = blockIdx.x;
  int tid = threadIdx.x, lane = tid & 63, wv = tid >> 6;

  int lo = 0, hi = nC;
  while (lo < hi) { int m = (lo + hi) >> 1; if (batch_c[m] < b) lo = m + 1; else hi = m; }
  int st = lo;
  hi = nC;
  while (lo < hi) { int m = (lo + hi) >> 1; if (batch_c[m] < b + 1) lo = m + 1; else hi = m; }
  int en = lo;

  float ax = 0.f, ay = 0.f;
  int r = st + wv;
  for (; r + 24 < en; r += 32) {
    unsigned u0 = hc2[((size_t)(r)      << 6) + lane];
    unsigned u1 = hc2[((size_t)(r + 8)  << 6) + lane];
    unsigned u2 = hc2[((size_t)(r + 16) << 6) + lane];
    unsigned u3 = hc2[((size_t)(r + 24) << 6) + lane];
    ax += bflo(u0) + bflo(u1) + bflo(u2) + bflo(u3);
    ay += bfhi(u0) + bfhi(u1) + bfhi(u2) + bfhi(u3);
  }
  for (; r < en; r += 8) {
    unsigned u = hc2[((size_t)r << 6) + lane];
    ax += bflo(u); ay += bfhi(u);
  }

  __shared__ float sg[8][128];
  sg[wv][2 * lane]     = ax;
  sg[wv][2 * lane + 1] = ay;
  __syncthreads();

  __shared__ float gf[128];
  if (tid < 128) {
    float s = 0.f;
#pragma unroll
    for (int i = 0; i < 8; ++i) s += sg[i][tid];
    float sc = (en > st) ? 1.0f / (float)(en - st) : 0.f;
    gf[tid] = s * sc;
  }
  __syncthreads();

  __shared__ float lg[12];
  __shared__ float lse_s;
  if (tid < NCLS) {
    const unsigned short* W    = WB + 768;     // [128][10] bf16
    const unsigned short* bias = WB + 2048;    // [10] bf16
    float acc = bflo((unsigned)bias[tid]);
    for (int k = 0; k < 128; ++k)
      acc += gf[k] * bflo((unsigned)W[k * NCLS + tid]);
    lg[tid] = acc;
  }
  __syncthreads();
  if (tid == 0) {
    float m = lg[0];
    for (int c = 1; c < NCLS; ++c) m = fmaxf(m, lg[c]);
    float se = 0.f;
    for (int c = 0; c < NCLS; ++c) se += expf(lg[c] - m);
    lse_s = logf(se) + m;
  }
  __syncthreads();
  if (tid < NCLS) {
    float o = lg[tid] - lse_s;
    if (*flag) ((unsigned short*)out)[b * NCLS + tid] = f2bf(o);
    else       ((float*)out)[b * NCLS + tid] = o;
  }
}

static void build_csr(const int* src, const int* dst, int n, int nE,
                      int* rp, int* cur, int* colv, int* bsum, hipStream_t stream) {
  int nb = (n + SCAN_CHUNK - 1) / SCAN_CHUNK;
  hipMemsetAsync(cur, 0, (size_t)n * 4, stream);
  count_deg<<<(nE + 255) / 256, 256, 0, stream>>>(dst, cur, nE);
  scan_bsum<<<nb, 256, 0, stream>>>(cur, bsum, n);
  scan_top<<<1, 64, 0, stream>>>(bsum, nb);
  scan_write<<<nb, 256, 0, stream>>>(cur, bsum, rp, n, nE);
  copy_int<<<(n + 255) / 256, 256, 0, stream>>>(rp, cur, n);
  fill_csr<<<(nE + 255) / 256, 256, 0, stream>>>(src, dst, cur, colv, nE);
}

extern "C" void kernel_launch(void* const* d_in, const int* in_sizes, int n_in,
                              void* d_out, int out_size, void* d_ws, size_t ws_size,
                              hipStream_t stream) {
  (void)in_sizes; (void)n_in; (void)out_size; (void)ws_size;
  const void* x        = d_in[0];
  const int*  ei       = (const int*)d_in[1];
  const int*  src      = ei;
  const int*  dst      = ei + N_EDGES;
  const int*  ci       = (const int*)d_in[3];
  const int*  cn       = ci;                // cover: node ids (sources)
  const int*  cc       = ci + N_MEMB;       // cover: cluster ids (dests)
  const int*  eip      = (const int*)d_in[4];
  const int*  srcp     = eip;
  const int*  dstp     = eip + N_EDGESP;
  const int*  batch_c  = (const int*)d_in[5];
  const void* lin2_W   = d_in[6];
  const void* lin2_b   = d_in[7];
  const void* in_c1_Wl = d_in[8];  const void* in_c1_bl = d_in[9];  const void* in_c1_Wr = d_in[10];
  const void* in_c2_Wl = d_in[11]; const void* in_c2_bl = d_in[12]; const void* in_c2_Wr = d_in[13];
  const void* in_lin_W = d_in[14]; const void* in_lin_b = d_in[15];
  const void* b1_c1_Wl = d_in[16]; const void* b1_c1_bl = d_in[17]; const void* b1_c1_Wr = d_in[18];
  const void* b1_c2_Wl = d_in[19]; const void* b1_c2_bl = d_in[20]; const void* b1_c2_Wr = d_in[21];
  const void* b1_lin_W = d_in[22]; const void* b1_lin_b = d_in[23];

  char* base = (char*)d_ws;
  unsigned short* A0 = (unsigned short*)(base + OFF_A0);
  unsigned short* A1 = (unsigned short*)(base + OFF_A1);
  unsigned short* A2 = (unsigned short*)(base + OFF_A2);
  unsigned short* xB = (unsigned short*)(base + OFF_XB);
  uint4* wp0 = (uint4*)(base + OFF_WP);
  unsigned short* WBp = (unsigned short*)(base + OFF_WB);
  int*   ib  = (int*)(base + OFF_IB);
  int *nrp = ib + I_NRP, *ncur = ib + I_NCUR, *ncol = ib + I_NCOL;
  int *crp = ib + I_CRP, *ccur = ib + I_CCUR, *ccol = ib + I_CCOL;
  int *mrp = ib + I_MRP, *mcur = ib + I_MCUR, *mcol = ib + I_MCOL;
  int *bsum = ib + I_BSUM;
  int *flag = ib + I_FLAG;

#define WPK(L) (wp0 + (L) * 4096)

  probe_dtype<<<1, 64, 0, stream>>>((const unsigned short*)x, flag);

  // ---- dtype-generic ingestion: everything -> bf16 ----
  cvt_x<<<6250, 256, 0, stream>>>(x, (uint4*)xB, flag);
  pack_w<<<16, 256, 0, stream>>>(in_c1_Wl, in_c1_Wr, 0,     WPK(0), flag);
  pack_w<<<16, 256, 0, stream>>>(in_c2_Wl, in_c2_Wr, 0,     WPK(1), flag);
  pack_w<<<16, 256, 0, stream>>>(in_lin_W, in_lin_W, 16384, WPK(2), flag);
  pack_w<<<16, 256, 0, stream>>>(b1_c1_Wl, b1_c1_Wr, 0,     WPK(3), flag);
  pack_w<<<16, 256, 0, stream>>>(b1_c2_Wl, b1_c2_Wr, 0,     WPK(4), flag);
  pack_w<<<16, 256, 0, stream>>>(b1_lin_W, b1_lin_W, 16384, WPK(5), flag);
  cvt_small<<<9, 256, 0, stream>>>(in_c1_bl, in_c2_bl, in_lin_b,
                                   b1_c1_bl, b1_c2_bl, b1_lin_b,
                                   lin2_W, lin2_b, WBp, flag);

  // ---- CSRs ----
  build_csr(src,  dst,  N_NODES, N_EDGES,  nrp, ncur, ncol, bsum, stream);
  build_csr(cn,   cc,   N_CLUST, N_MEMB,   mrp, mcur, mcol, bsum, stream);
  build_csr(srcp, dstp, N_CLUST, N_EDGESP, crp, ccur, ccol, bsum, stream);

  int gN = (N_NODES + 63) / 64, gC = (N_CLUST + 63) / 64;

  // ---- node block ----
  gather_mean_bf16<<<N_NODES / 4, 256, 0, stream>>>((const unsigned*)xB, nrp, ncol, (unsigned*)A0, N_NODES);
  conv_mfma<<<gN, 256, 0, stream>>>(A0, xB, WPK(0), WBp + 0,   A1, N_NODES);
  gather_mean_bf16<<<N_NODES / 4, 256, 0, stream>>>((const unsigned*)A1, nrp, ncol, (unsigned*)A0, N_NODES);
  conv_mfma<<<gN, 256, 0, stream>>>(A0, A1, WPK(1), WBp + 128, A2, N_NODES);
  conv_mfma<<<gN, 256, 0, stream>>>(A1, A2, WPK(2), WBp + 256, A0, N_NODES);     // h -> A0

  // ---- cover pool: h -> hc (A1) ----
  gather_mean_bf16<<<N_CLUST / 4, 256, 0, stream>>>((const unsigned*)A0, mrp, mcol, (unsigned*)A1, N_CLUST);

  // ---- cluster block ----
  gather_mean_bf16<<<N_CLUST / 4, 256, 0, stream>>>((const unsigned*)A1, crp, ccol, (unsigned*)A2, N_CLUST);
  conv_mfma<<<gC, 256, 0, stream>>>(A2, A1, WPK(3), WBp + 384, A0, N_CLUST);     // xc1 -> A0
  gather_mean_bf16<<<N_CLUST / 4, 256, 0, stream>>>((const unsigned*)A0, crp, ccol, (unsigned*)A2, N_CLUST);
  conv_mfma<<<gC, 256, 0, stream>>>(A2, A0, WPK(4), WBp + 512, A1, N_CLUST);     // xc2 -> A1
  conv_mfma<<<gC, 256, 0, stream>>>(A0, A1, WPK(5), WBp + 640, A2, N_CLUST);     // hc2 -> A2

  // ---- fused global mean pool + head ----
  pool_head<<<NB, 512, 0, stream>>>((const unsigned*)A2, batch_c, WBp, d_out, flag, N_CLUST);
}

// Round 6
// 584.619 us; speedup vs baseline: 32.0064x; 1.2924x over previous
//
#include <hip/hip_runtime.h>
#include <hip/hip_bf16.h>

// ---- problem constants ----
#define N_NODES   100000
#define N_EDGES   1600000
#define N_MEMB    150000
#define N_CLUST   40000
#define N_EDGESP  800000
#define NB        64
#define NCLS      10

typedef __attribute__((ext_vector_type(4))) float f32x4;
typedef __attribute__((ext_vector_type(8))) short bf16x8;

// ---- workspace layout (byte offsets) ----
#define OFF_A0   0ul            // bf16 activation arena 0 (100000x128)
#define OFF_A1   25600000ul     // arena 1
#define OFF_A2   51200000ul     // arena 2
#define OFF_XB   76800000ul     // converted-input arena (bf16)
#define OFF_WP   102400000ul    // packed weights: 6 x 65536 B
#define OFF_WB   102793216ul    // converted biases + head weights (bf16)
#define OFF_IB   102801408ul    // int region (16B aligned)
// int region offsets (ints)
#define I_PART  0               // edge partition buffer (uint2 x 1.6M = 3.2M ints)
#define I_NRP   3200000         // node rowptr 100001
#define I_NCOL  3300004
#define I_CRP   4900004         // cluster rowptr 40001
#define I_CCOL  4940008
#define I_MRP   5740008         // memb rowptr 40001
#define I_MCOL  5780012
#define I_BCNT  5930016         // 3 x 64
#define I_PST   5930208         // 3 x 68 (65 used)
#define I_BCUR  5930412         // 3 x 64
#define I_FLAG  5930604
// end ~5.93M ints => total ws ~126.5 MB (harness provides >=165 MB, proven round 2)

#define PART_BLOCK 4096         // edges per partition block (512 thr x 8)

__device__ __forceinline__ unsigned short f2bf(float f) {   // RNE round
  unsigned u = __float_as_uint(f);
  return (unsigned short)((u + 0x7FFFu + ((u >> 16) & 1u)) >> 16);
}
__device__ __forceinline__ float bflo(unsigned u) { return __uint_as_float(u << 16); }
__device__ __forceinline__ float bfhi(unsigned u) { return __uint_as_float(u & 0xFFFF0000u); }

// Detect whether "float" inputs are bf16 (flag=1) or f32 (flag=0).
__global__ void probe_dtype(const unsigned short* __restrict__ x, int* __restrict__ flag) {
  if (blockIdx.x != 0 || threadIdx.x != 0) return;
  int wild = 0;
  for (int i = 0; i < 1024; i += 2) {
    int e = (x[i] >> 7) & 0xFF;
    if (e > 0x85) wild++;
  }
  *flag = (wild < 8) ? 1 : 0;
}

// convert external x (f32 or bf16 per flag) -> bf16 arena; 8 elts/thread
__global__ __launch_bounds__(256) void cvt_x(const void* __restrict__ x, uint4* __restrict__ xB,
                                             const int* __restrict__ flag) {
  int gid = blockIdx.x * 256 + threadIdx.x;
  if (gid >= 1600000) return;
  if (*flag) {
    xB[gid] = ((const uint4*)x)[gid];
  } else {
    const float4* xf = (const float4*)x;
    float4 a = xf[2 * gid], b = xf[2 * gid + 1];
    unsigned short v[8] __attribute__((aligned(16)));
    v[0] = f2bf(a.x); v[1] = f2bf(a.y); v[2] = f2bf(a.z); v[3] = f2bf(a.w);
    v[4] = f2bf(b.x); v[5] = f2bf(b.y); v[6] = f2bf(b.z); v[7] = f2bf(b.w);
    xB[gid] = *(const uint4*)v;
  }
}

// convert 6 bias vecs (128) + lin2_W (1280) + lin2_b (10) -> bf16 block
__global__ void cvt_small(const void* b0, const void* b1, const void* b2,
                          const void* b3, const void* b4, const void* b5,
                          const void* w2, const void* bb2,
                          unsigned short* __restrict__ dst, const int* __restrict__ flag) {
  int isb = *flag;
  int gid = blockIdx.x * 256 + threadIdx.x;
  const void* src; int local;
  if (gid < 768) {
    int seg = gid >> 7; local = gid & 127;
    src = (seg == 0) ? b0 : (seg == 1) ? b1 : (seg == 2) ? b2 : (seg == 3) ? b3 : (seg == 4) ? b4 : b5;
  } else if (gid < 2048) { src = w2;  local = gid - 768; }
  else if (gid < 2058)   { src = bb2; local = gid - 2048; }
  else return;
  dst[gid] = isb ? ((const unsigned short*)src)[local] : f2bf(((const float*)src)[local]);
}

// ============ binned CSR build ============
// buckets of 2048 dst nodes (bucket = dst >> 11), nbuck <= 64.

__global__ __launch_bounds__(512) void bucket_count(const int* __restrict__ dstI, int nE,
                                                    int* __restrict__ bcnt, int nbuck) {
  __shared__ int h[64];
  int tid = threadIdx.x;
  if (tid < 64) h[tid] = 0;
  __syncthreads();
  int base = blockIdx.x * PART_BLOCK + tid;
#pragma unroll
  for (int j = 0; j < 8; ++j) {
    int i = base + j * 512;
    if (i < nE) atomicAdd(&h[dstI[i] >> 11], 1);
  }
  __syncthreads();
  if (tid < nbuck && h[tid]) atomicAdd(&bcnt[tid], h[tid]);
}

// exclusive scan of bcnt -> pstart[0..nbuck], init bcur = pstart
__global__ void bucket_scan(const int* __restrict__ bcnt, int* __restrict__ pstart,
                            int* __restrict__ bcur, int nbuck) {
  int lane = threadIdx.x;                      // 64 threads
  int v = (lane < nbuck) ? bcnt[lane] : 0;
  int inc = v;
  for (int off = 1; off < 64; off <<= 1) {
    int u = __shfl_up(inc, off);
    if (lane >= off) inc += u;
  }
  if (lane < nbuck) { pstart[lane] = inc - v; bcur[lane] = inc - v; }
  if (lane == 63) pstart[nbuck] = inc;
}

// scatter (src,dst) into contiguous per-bucket partitions (block-reserved ranges)
__global__ __launch_bounds__(512) void partition_edges(
    const int* __restrict__ srcI, const int* __restrict__ dstI, int nE,
    int* __restrict__ bcur, uint2* __restrict__ part, int nbuck) {
  __shared__ int h[64], lcur[64];
  int tid = threadIdx.x;
  if (tid < 64) h[tid] = 0;
  __syncthreads();
  int base = blockIdx.x * PART_BLOCK + tid;
  int s[8], d[8], bk[8];
#pragma unroll
  for (int j = 0; j < 8; ++j) {
    int i = base + j * 512;
    if (i < nE) { d[j] = dstI[i]; s[j] = srcI[i]; bk[j] = d[j] >> 11; atomicAdd(&h[bk[j]], 1); }
    else bk[j] = -1;
  }
  __syncthreads();
  if (tid < nbuck && h[tid]) lcur[tid] = atomicAdd(&bcur[tid], h[tid]);
  __syncthreads();
#pragma unroll
  for (int j = 0; j < 8; ++j) {
    if (bk[j] >= 0) {
      int p = atomicAdd(&lcur[bk[j]], 1);
      part[p] = make_uint2((unsigned)s[j], (unsigned)d[j]);
    }
  }
}

// one workgroup per bucket: LDS deg histogram -> LDS scan -> write rowptr,
// then LDS-cursor scatter of col (writes confined to <=128 KB L2 window).
__global__ __launch_bounds__(1024) void binned_fill(
    const uint2* __restrict__ part, const int* __restrict__ pstart,
    int* __restrict__ rowptr, int* __restrict__ col, int n, int nbuck) {
  __shared__ int cnt[2048];
  __shared__ int wsum[16];
  int b = blockIdx.x, tid = threadIdx.x;
  int nbase = b << 11;
  int nn = n - nbase; if (nn > 2048) nn = 2048;
  cnt[tid] = 0; cnt[tid + 1024] = 0;
  __syncthreads();
  int e0 = pstart[b], e1 = pstart[b + 1];
  for (int e = e0 + tid; e < e1; e += 1024)
    atomicAdd(&cnt[part[e].y - nbase], 1);
  __syncthreads();
  // exclusive scan of 2048 counts (thread owns elems 2t, 2t+1)
  int c0 = cnt[2 * tid], c1 = cnt[2 * tid + 1];
  int s = c0 + c1;
  int lane = tid & 63, wv = tid >> 6;
  int inc = s;
  for (int off = 1; off < 64; off <<= 1) {
    int u = __shfl_up(inc, off);
    if (lane >= off) inc += u;
  }
  if (lane == 63) wsum[wv] = inc;
  __syncthreads();
  int woff = 0;
  for (int k = 0; k < wv; ++k) woff += wsum[k];
  int excl = woff + (inc - s);
  int r0 = e0 + excl;
  int r1 = r0 + c0;
  __syncthreads();                 // cnt reads done before overwrite
  cnt[2 * tid] = r0; cnt[2 * tid + 1] = r1;
  if (2 * tid < nn)     rowptr[nbase + 2 * tid]     = r0;
  if (2 * tid + 1 < nn) rowptr[nbase + 2 * tid + 1] = r1;
  __syncthreads();
  for (int e = e0 + tid; e < e1; e += 1024) {
    uint2 ed = part[e];
    int p = atomicAdd(&cnt[ed.y - nbase], 1);
    col[p] = (int)ed.x;
  }
  if (b == nbuck - 1 && tid == 0) rowptr[n] = pstart[nbuck];
}

// ============ pull-mode mean aggregation, bf16 rows (256 B) ============
// one wave per dst row; lane owns 2 features; 8-deep unroll for MLP
__global__ __launch_bounds__(256) void gather_mean_bf16(
    const unsigned* __restrict__ x, const int* __restrict__ rowptr, const int* __restrict__ col,
    unsigned* __restrict__ out, int n) {
  int w = (blockIdx.x * 256 + threadIdx.x) >> 6;
  if (w >= n) return;
  int lane = threadIdx.x & 63;
  int s0 = rowptr[w], s1 = rowptr[w + 1];
  float ax = 0.f, ay = 0.f;
  int j = s0;
  for (; j + 7 < s1; j += 8) {
    unsigned u0 = x[((size_t)col[j]     << 6) + lane];
    unsigned u1 = x[((size_t)col[j + 1] << 6) + lane];
    unsigned u2 = x[((size_t)col[j + 2] << 6) + lane];
    unsigned u3 = x[((size_t)col[j + 3] << 6) + lane];
    unsigned u4 = x[((size_t)col[j + 4] << 6) + lane];
    unsigned u5 = x[((size_t)col[j + 5] << 6) + lane];
    unsigned u6 = x[((size_t)col[j + 6] << 6) + lane];
    unsigned u7 = x[((size_t)col[j + 7] << 6) + lane];
    ax += bflo(u0) + bflo(u1) + bflo(u2) + bflo(u3) + bflo(u4) + bflo(u5) + bflo(u6) + bflo(u7);
    ay += bfhi(u0) + bfhi(u1) + bfhi(u2) + bfhi(u3) + bfhi(u4) + bfhi(u5) + bfhi(u6) + bfhi(u7);
  }
  for (; j < s1; ++j) {
    unsigned u = x[((size_t)col[j] << 6) + lane];
    ax += bflo(u); ay += bfhi(u);
  }
  float sc = (s1 > s0) ? 1.0f / (float)(s1 - s0) : 0.f;
  unsigned r = (unsigned)f2bf(ax * sc) | ((unsigned)f2bf(ay * sc) << 16);
  out[((size_t)w << 6) + lane] = r;
}

// ============ weight pre-pack into MFMA A-fragment order ============
__global__ __launch_bounds__(256) void pack_w(const void* __restrict__ Wlv, const void* __restrict__ Wrv,
                                              int wrOff, uint4* __restrict__ dst,
                                              const int* __restrict__ flag) {
  int isb = *flag;
  int t = blockIdx.x * 256 + threadIdx.x;      // 16 blocks x 256 = 4096
  int lane = t & 63, mt = (t >> 6) & 7, ks = t >> 9;
  int feat = mt * 16 + (lane & 15);
  int k0 = ks * 32 + (lane >> 4) * 8;
  unsigned short v[8] __attribute__((aligned(16)));
#pragma unroll
  for (int j = 0; j < 8; ++j) {
    int k = k0 + j;
    int idx = ((k < 128) ? k * 128 : (k - 128) * 128 + wrOff) + feat;
    const void* W = (k < 128) ? Wlv : Wrv;
    v[j] = isb ? ((const unsigned short*)W)[idx] : f2bf(((const float*)W)[idx]);
  }
  dst[t] = *(const uint4*)v;
}

// ============ MFMA conv: out = relu([A|X] @ [Wl;Wr] + b), K=256 ============
__global__ __launch_bounds__(256) void conv_mfma(
    const unsigned short* __restrict__ Abuf, const unsigned short* __restrict__ Xbuf,
    const uint4* __restrict__ Wp, const unsigned short* __restrict__ bias,
    unsigned short* __restrict__ out, int nrows) {
  __shared__ uint4 lds[2048];                  // 32 KB
  int tid = threadIdx.x;
  int row0 = blockIdx.x * 64;

  const char* Ab = (const char*)Abuf;
  const char* Xb = (const char*)Xbuf;
  for (int c = tid; c < 2048; c += 256) {
    int r = c >> 5, seg = c & 31;
    int gr = row0 + r;
    uint4 v = make_uint4(0u, 0u, 0u, 0u);
    if (gr < nrows) {
      const char* srcp = (seg < 16) ? (Ab + (size_t)gr * 256 + seg * 16)
                                    : (Xb + (size_t)gr * 256 + (seg - 16) * 16);
      v = *(const uint4*)srcp;
    }
    int byteoff = (r << 9) + ((seg << 4) ^ ((r & 7) << 4));
    *(uint4*)((char*)lds + byteoff) = v;
  }
  __syncthreads();

  int lane = tid & 63, w = tid >> 6;
  int brow = 16 * w + (lane & 15);
  int q = lane >> 4;
  int q16 = q << 4;

  f32x4 acc[8];
#pragma unroll
  for (int mt = 0; mt < 8; ++mt) acc[mt] = (f32x4){0.f, 0.f, 0.f, 0.f};

  const uint4* wp_lane = Wp + lane;
  int bbase = brow << 9;
  int bxor = (brow & 7) << 4;

  for (int ks = 0; ks < 8; ++ks) {
    int koff = ks * 64 + q16;
    uint4 bv = *(const uint4*)((const char*)lds + bbase + (koff ^ bxor));
    bf16x8 bfrag = __builtin_bit_cast(bf16x8, bv);
#pragma unroll
    for (int mt = 0; mt < 8; ++mt) {
      uint4 av = wp_lane[(ks * 8 + mt) * 64];
      bf16x8 afrag = __builtin_bit_cast(bf16x8, av);
      acc[mt] = __builtin_amdgcn_mfma_f32_16x16x32_bf16(afrag, bfrag, acc[mt], 0, 0, 0);
    }
  }

  int orow = row0 + brow;
  if (orow < nrows) {
    unsigned short* op = out + (size_t)orow * 128;
#pragma unroll
    for (int mt = 0; mt < 8; ++mt) {
      int f0 = mt * 16 + q * 4;
      unsigned b01 = *(const unsigned*)(bias + f0);
      unsigned b23 = *(const unsigned*)(bias + f0 + 2);
      float v0 = fmaxf(acc[mt][0] + bflo(b01), 0.f);
      float v1 = fmaxf(acc[mt][1] + bfhi(b01), 0.f);
      float v2 = fmaxf(acc[mt][2] + bflo(b23), 0.f);
      float v3 = fmaxf(acc[mt][3] + bfhi(b23), 0.f);
      uint2 pk;
      pk.x = (unsigned)f2bf(v0) | ((unsigned)f2bf(v1) << 16);
      pk.y = (unsigned)f2bf(v2) | ((unsigned)f2bf(v3) << 16);
      *(uint2*)(op + f0) = pk;
    }
  }
}

// ============ fused batch mean pool + head (per-graph block) ============
__global__ __launch_bounds__(512) void pool_head(
    const unsigned* __restrict__ hc2, const int* __restrict__ batch_c,
    const unsigned short* __restrict__ WB, void* __restrict__ out,
    const int* __restrict__ flag, int nC) {
  int b = blockIdx.x;
  int tid = threadIdx.x, lane = tid & 63, wv = tid >> 6;

  int lo = 0, hi = nC;
  while (lo < hi) { int m = (lo + hi) >> 1; if (batch_c[m] < b) lo = m + 1; else hi = m; }
  int st = lo;
  hi = nC;
  while (lo < hi) { int m = (lo + hi) >> 1; if (batch_c[m] < b + 1) lo = m + 1; else hi = m; }
  int en = lo;

  float ax = 0.f, ay = 0.f;
  int r = st + wv;
  for (; r + 24 < en; r += 32) {
    unsigned u0 = hc2[((size_t)(r)      << 6) + lane];
    unsigned u1 = hc2[((size_t)(r + 8)  << 6) + lane];
    unsigned u2 = hc2[((size_t)(r + 16) << 6) + lane];
    unsigned u3 = hc2[((size_t)(r + 24) << 6) + lane];
    ax += bflo(u0) + bflo(u1) + bflo(u2) + bflo(u3);
    ay += bfhi(u0) + bfhi(u1) + bfhi(u2) + bfhi(u3);
  }
  for (; r < en; r += 8) {
    unsigned u = hc2[((size_t)r << 6) + lane];
    ax += bflo(u); ay += bfhi(u);
  }

  __shared__ float sg[8][128];
  sg[wv][2 * lane]     = ax;
  sg[wv][2 * lane + 1] = ay;
  __syncthreads();

  __shared__ float gf[128];
  if (tid < 128) {
    float s = 0.f;
#pragma unroll
    for (int i = 0; i < 8; ++i) s += sg[i][tid];
    float sc = (en > st) ? 1.0f / (float)(en - st) : 0.f;
    gf[tid] = s * sc;
  }
  __syncthreads();

  __shared__ float lg[12];
  __shared__ float lse_s;
  if (tid < NCLS) {
    const unsigned short* W    = WB + 768;     // [128][10] bf16
    const unsigned short* bias = WB + 2048;    // [10] bf16
    float acc = bflo((unsigned)bias[tid]);
    for (int k = 0; k < 128; ++k)
      acc += gf[k] * bflo((unsigned)W[k * NCLS + tid]);
    lg[tid] = acc;
  }
  __syncthreads();
  if (tid == 0) {
    float m = lg[0];
    for (int c = 1; c < NCLS; ++c) m = fmaxf(m, lg[c]);
    float se = 0.f;
    for (int c = 0; c < NCLS; ++c) se += expf(lg[c] - m);
    lse_s = logf(se) + m;
  }
  __syncthreads();
  if (tid < NCLS) {
    float o = lg[tid] - lse_s;
    if (*flag) ((unsigned short*)out)[b * NCLS + tid] = f2bf(o);
    else       ((float*)out)[b * NCLS + tid] = o;
  }
}

static void build_csr2(const int* src, const int* dstI, int n, int nE,
                       int* rp, int* colv, uint2* part,
                       int* bcnt, int* pst, int* bcur, hipStream_t stream) {
  int nbuck = (n + 2047) >> 11;
  int nblk = (nE + PART_BLOCK - 1) / PART_BLOCK;
  bucket_count<<<nblk, 512, 0, stream>>>(dstI, nE, bcnt, nbuck);
  bucket_scan<<<1, 64, 0, stream>>>(bcnt, pst, bcur, nbuck);
  partition_edges<<<nblk, 512, 0, stream>>>(src, dstI, nE, bcur, part, nbuck);
  binned_fill<<<nbuck, 1024, 0, stream>>>(part, pst, rp, colv, n, nbuck);
}

extern "C" void kernel_launch(void* const* d_in, const int* in_sizes, int n_in,
                              void* d_out, int out_size, void* d_ws, size_t ws_size,
                              hipStream_t stream) {
  (void)in_sizes; (void)n_in; (void)out_size; (void)ws_size;
  const void* x        = d_in[0];
  const int*  ei       = (const int*)d_in[1];
  const int*  src      = ei;
  const int*  dst      = ei + N_EDGES;
  const int*  ci       = (const int*)d_in[3];
  const int*  cn       = ci;                // cover: node ids (sources)
  const int*  cc       = ci + N_MEMB;       // cover: cluster ids (dests)
  const int*  eip      = (const int*)d_in[4];
  const int*  srcp     = eip;
  const int*  dstp     = eip + N_EDGESP;
  const int*  batch_c  = (const int*)d_in[5];
  const void* lin2_W   = d_in[6];
  const void* lin2_b   = d_in[7];
  const void* in_c1_Wl = d_in[8];  const void* in_c1_bl = d_in[9];  const void* in_c1_Wr = d_in[10];
  const void* in_c2_Wl = d_in[11]; const void* in_c2_bl = d_in[12]; const void* in_c2_Wr = d_in[13];
  const void* in_lin_W = d_in[14]; const void* in_lin_b = d_in[15];
  const void* b1_c1_Wl = d_in[16]; const void* b1_c1_bl = d_in[17]; const void* b1_c1_Wr = d_in[18];
  const void* b1_c2_Wl = d_in[19]; const void* b1_c2_bl = d_in[20]; const void* b1_c2_Wr = d_in[21];
  const void* b1_lin_W = d_in[22]; const void* b1_lin_b = d_in[23];

  char* base = (char*)d_ws;
  unsigned short* A0 = (unsigned short*)(base + OFF_A0);
  unsigned short* A1 = (unsigned short*)(base + OFF_A1);
  unsigned short* A2 = (unsigned short*)(base + OFF_A2);
  unsigned short* xB = (unsigned short*)(base + OFF_XB);
  uint4* wp0 = (uint4*)(base + OFF_WP);
  unsigned short* WBp = (unsigned short*)(base + OFF_WB);
  int*   ib  = (int*)(base + OFF_IB);
  uint2* part = (uint2*)(ib + I_PART);
  int *nrp = ib + I_NRP, *ncol = ib + I_NCOL;
  int *crp = ib + I_CRP, *ccol = ib + I_CCOL;
  int *mrp = ib + I_MRP, *mcol = ib + I_MCOL;
  int *bcnt = ib + I_BCNT;                  // 3 x 64
  int *pst  = ib + I_PST;                   // 3 x 68
  int *bcur = ib + I_BCUR;                  // 3 x 64
  int *flag = ib + I_FLAG;

#define WPK(L) (wp0 + (L) * 4096)

  probe_dtype<<<1, 64, 0, stream>>>((const unsigned short*)x, flag);

  // ---- dtype-generic ingestion: everything -> bf16 ----
  cvt_x<<<6250, 256, 0, stream>>>(x, (uint4*)xB, flag);
  pack_w<<<16, 256, 0, stream>>>(in_c1_Wl, in_c1_Wr, 0,     WPK(0), flag);
  pack_w<<<16, 256, 0, stream>>>(in_c2_Wl, in_c2_Wr, 0,     WPK(1), flag);
  pack_w<<<16, 256, 0, stream>>>(in_lin_W, in_lin_W, 16384, WPK(2), flag);
  pack_w<<<16, 256, 0, stream>>>(b1_c1_Wl, b1_c1_Wr, 0,     WPK(3), flag);
  pack_w<<<16, 256, 0, stream>>>(b1_c2_Wl, b1_c2_Wr, 0,     WPK(4), flag);
  pack_w<<<16, 256, 0, stream>>>(b1_lin_W, b1_lin_W, 16384, WPK(5), flag);
  cvt_small<<<9, 256, 0, stream>>>(in_c1_bl, in_c2_bl, in_lin_b,
                                   b1_c1_bl, b1_c2_bl, b1_lin_b,
                                   lin2_W, lin2_b, WBp, flag);

  // ---- CSRs (binned build; part buffer reused sequentially) ----
  hipMemsetAsync(bcnt, 0, 192 * 4, stream);
  build_csr2(src,  dst,  N_NODES, N_EDGES,  nrp, ncol, part, bcnt,       pst,        bcur,       stream);
  build_csr2(cn,   cc,   N_CLUST, N_MEMB,   mrp, mcol, part, bcnt + 64,  pst + 68,   bcur + 64,  stream);
  build_csr2(srcp, dstp, N_CLUST, N_EDGESP, crp, ccol, part, bcnt + 128, pst + 136,  bcur + 128, stream);

  int gN = (N_NODES + 63) / 64, gC = (N_CLUST + 63) / 64;

  // ---- node block ----
  gather_mean_bf16<<<N_NODES / 4, 256, 0, stream>>>((const unsigned*)xB, nrp, ncol, (unsigned*)A0, N_NODES);
  conv_mfma<<<gN, 256, 0, stream>>>(A0, xB, WPK(0), WBp + 0,   A1, N_NODES);
  gather_mean_bf16<<<N_NODES / 4, 256, 0, stream>>>((const unsigned*)A1, nrp, ncol, (unsigned*)A0, N_NODES);
  conv_mfma<<<gN, 256, 0, stream>>>(A0, A1, WPK(1), WBp + 128, A2, N_NODES);
  conv_mfma<<<gN, 256, 0, stream>>>(A1, A2, WPK(2), WBp + 256, A0, N_NODES);     // h -> A0

  // ---- cover pool: h -> hc (A1) ----
  gather_mean_bf16<<<N_CLUST / 4, 256, 0, stream>>>((const unsigned*)A0, mrp, mcol, (unsigned*)A1, N_CLUST);

  // ---- cluster block ----
  gather_mean_bf16<<<N_CLUST / 4, 256, 0, stream>>>((const unsigned*)A1, crp, ccol, (unsigned*)A2, N_CLUST);
  conv_mfma<<<gC, 256, 0, stream>>>(A2, A1, WPK(3), WBp + 384, A0, N_CLUST);     // xc1 -> A0
  gather_mean_bf16<<<N_CLUST / 4, 256, 0, stream>>>((const unsigned*)A0, crp, ccol, (unsigned*)A2, N_CLUST);
  conv_mfma<<<gC, 256, 0, stream>>>(A2, A0, WPK(4), WBp + 512, A1, N_CLUST);     // xc2 -> A1
  conv_mfma<<<gC, 256, 0, stream>>>(A0, A1, WPK(5), WBp + 640, A2, N_CLUST);     // hc2 -> A2

  // ---- fused global mean pool + head ----
  pool_head<<<NB, 512, 0, stream>>>((const unsigned*)A2, batch_c, WBp, d_out, flag, N_CLUST);
}

// Round 7
// 564.662 us; speedup vs baseline: 33.1377x; 1.0353x over previous
//
#include <hip/hip_runtime.h>
#include <hip/hip_bf16.h>

// ---- problem constants ----
#define N_NODES   100000
#define N_EDGES   1600000
#define N_MEMB    150000
#define N_CLUST   40000
#define N_EDGESP  800000
#define NB        64
#define NCLS      10

typedef __attribute__((ext_vector_type(4))) float f32x4;
typedef __attribute__((ext_vector_type(8))) short bf16x8;

// ---- workspace layout (byte offsets) ----
#define OFF_A0   0ul            // bf16 activation arena 0 (100000x128)
#define OFF_A1   25600000ul     // arena 1
#define OFF_A2   51200000ul     // arena 2
#define OFF_XB   76800000ul     // converted-input arena (bf16)
#define OFF_WP   102400000ul    // packed weights: 6 x 65536 B
#define OFF_WB   102793216ul    // converted biases + head weights (bf16)
#define OFF_IB   102801408ul    // int region (16B aligned)
// int region offsets (ints)
#define I_PART  0               // packed edge partition buffer (uint x 1.6M)
#define I_NRP   3200000         // node rowptr 100001
#define I_NCOL  3300004
#define I_CRP   4900004         // cluster rowptr 40001
#define I_CCOL  4940008
#define I_MRP   5740008         // memb rowptr 40001
#define I_MCOL  5780012
#define I_BCNT  5930016         // 3 x 64
#define I_PST   5930208         // 3 x 68 (65 used)
#define I_BCUR  5930412         // 3 x 64
#define I_FLAG  5930604
// end ~5.93M ints => total ws ~126.5 MB

#define PART_BLOCK 4096         // edges per partition block (512 thr x 8)

__device__ __forceinline__ unsigned short f2bf(float f) {   // RNE round
  unsigned u = __float_as_uint(f);
  return (unsigned short)((u + 0x7FFFu + ((u >> 16) & 1u)) >> 16);
}
__device__ __forceinline__ float bflo(unsigned u) { return __uint_as_float(u << 16); }
__device__ __forceinline__ float bfhi(unsigned u) { return __uint_as_float(u & 0xFFFF0000u); }

// Detect whether "float" inputs are bf16 (flag=1) or f32 (flag=0).
__global__ void probe_dtype(const unsigned short* __restrict__ x, int* __restrict__ flag) {
  if (blockIdx.x != 0 || threadIdx.x != 0) return;
  int wild = 0;
  for (int i = 0; i < 1024; i += 2) {
    int e = (x[i] >> 7) & 0xFF;
    if (e > 0x85) wild++;
  }
  *flag = (wild < 8) ? 1 : 0;
}

// convert external x (f32 or bf16 per flag) -> bf16 arena; 8 elts/thread
__global__ __launch_bounds__(256) void cvt_x(const void* __restrict__ x, uint4* __restrict__ xB,
                                             const int* __restrict__ flag) {
  int gid = blockIdx.x * 256 + threadIdx.x;
  if (gid >= 1600000) return;
  if (*flag) {
    xB[gid] = ((const uint4*)x)[gid];
  } else {
    const float4* xf = (const float4*)x;
    float4 a = xf[2 * gid], b = xf[2 * gid + 1];
    unsigned short v[8] __attribute__((aligned(16)));
    v[0] = f2bf(a.x); v[1] = f2bf(a.y); v[2] = f2bf(a.z); v[3] = f2bf(a.w);
    v[4] = f2bf(b.x); v[5] = f2bf(b.y); v[6] = f2bf(b.z); v[7] = f2bf(b.w);
    xB[gid] = *(const uint4*)v;
  }
}

// convert 6 bias vecs (128) + lin2_W (1280) + lin2_b (10) -> bf16 block
__global__ void cvt_small(const void* b0, const void* b1, const void* b2,
                          const void* b3, const void* b4, const void* b5,
                          const void* w2, const void* bb2,
                          unsigned short* __restrict__ dst, const int* __restrict__ flag) {
  int isb = *flag;
  int gid = blockIdx.x * 256 + threadIdx.x;
  const void* src; int local;
  if (gid < 768) {
    int seg = gid >> 7; local = gid & 127;
    src = (seg == 0) ? b0 : (seg == 1) ? b1 : (seg == 2) ? b2 : (seg == 3) ? b3 : (seg == 4) ? b4 : b5;
  } else if (gid < 2048) { src = w2;  local = gid - 768; }
  else if (gid < 2058)   { src = bb2; local = gid - 2048; }
  else return;
  dst[gid] = isb ? ((const unsigned short*)src)[local] : f2bf(((const float*)src)[local]);
}

// ============ binned CSR build ============
// buckets of 2048 dst nodes (bucket = dst >> 11), nbuck <= 64.

__global__ __launch_bounds__(512) void bucket_count(const int* __restrict__ dstI, int nE,
                                                    int* __restrict__ bcnt, int nbuck) {
  __shared__ int h[64];
  int tid = threadIdx.x;
  if (tid < 64) h[tid] = 0;
  __syncthreads();
  int base = blockIdx.x * PART_BLOCK + tid;
#pragma unroll
  for (int j = 0; j < 8; ++j) {
    int i = base + j * 512;
    if (i < nE) atomicAdd(&h[dstI[i] >> 11], 1);
  }
  __syncthreads();
  if (tid < nbuck && h[tid]) atomicAdd(&bcnt[tid], h[tid]);
}

// exclusive scan of bcnt -> pstart[0..nbuck], init bcur = pstart
__global__ void bucket_scan(const int* __restrict__ bcnt, int* __restrict__ pstart,
                            int* __restrict__ bcur, int nbuck) {
  int lane = threadIdx.x;                      // 64 threads
  int v = (lane < nbuck) ? bcnt[lane] : 0;
  int inc = v;
  for (int off = 1; off < 64; off <<= 1) {
    int u = __shfl_up(inc, off);
    if (lane >= off) inc += u;
  }
  if (lane < nbuck) { pstart[lane] = inc - v; bcur[lane] = inc - v; }
  if (lane == 63) pstart[nbuck] = inc;
}

// scatter packed (src | local_dst<<17) into per-bucket partitions
__global__ __launch_bounds__(512) void partition_edges(
    const int* __restrict__ srcI, const int* __restrict__ dstI, int nE,
    int* __restrict__ bcur, unsigned* __restrict__ part, int nbuck) {
  __shared__ int h[64], lcur[64];
  int tid = threadIdx.x;
  if (tid < 64) h[tid] = 0;
  __syncthreads();
  int base = blockIdx.x * PART_BLOCK + tid;
  int s[8], d[8], bk[8];
#pragma unroll
  for (int j = 0; j < 8; ++j) {
    int i = base + j * 512;
    if (i < nE) { d[j] = dstI[i]; s[j] = srcI[i]; bk[j] = d[j] >> 11; atomicAdd(&h[bk[j]], 1); }
    else bk[j] = -1;
  }
  __syncthreads();
  if (tid < nbuck && h[tid]) lcur[tid] = atomicAdd(&bcur[tid], h[tid]);
  __syncthreads();
#pragma unroll
  for (int j = 0; j < 8; ++j) {
    if (bk[j] >= 0) {
      int p = atomicAdd(&lcur[bk[j]], 1);
      part[p] = (unsigned)s[j] | ((unsigned)(d[j] & 2047) << 17);
    }
  }
}

// one workgroup per bucket: LDS deg histogram -> LDS scan -> rowptr,
// then LDS-cursor scatter of col (writes confined to <=128 KB L2 window).
__global__ __launch_bounds__(1024) void binned_fill(
    const unsigned* __restrict__ part, const int* __restrict__ pstart,
    int* __restrict__ rowptr, int* __restrict__ col, int n, int nbuck) {
  __shared__ int cnt[2048];
  __shared__ int wsum[16];
  int b = blockIdx.x, tid = threadIdx.x;
  int nbase = b << 11;
  int nn = n - nbase; if (nn > 2048) nn = 2048;
  cnt[tid] = 0; cnt[tid + 1024] = 0;
  __syncthreads();
  int e0 = pstart[b], e1 = pstart[b + 1];
  for (int e = e0 + tid; e < e1; e += 1024)
    atomicAdd(&cnt[part[e] >> 17], 1);
  __syncthreads();
  int c0 = cnt[2 * tid], c1 = cnt[2 * tid + 1];
  int s = c0 + c1;
  int lane = tid & 63, wv = tid >> 6;
  int inc = s;
  for (int off = 1; off < 64; off <<= 1) {
    int u = __shfl_up(inc, off);
    if (lane >= off) inc += u;
  }
  if (lane == 63) wsum[wv] = inc;
  __syncthreads();
  int woff = 0;
  for (int k = 0; k < wv; ++k) woff += wsum[k];
  int excl = woff + (inc - s);
  int r0 = e0 + excl;
  int r1 = r0 + c0;
  __syncthreads();
  cnt[2 * tid] = r0; cnt[2 * tid + 1] = r1;
  if (2 * tid < nn)     rowptr[nbase + 2 * tid]     = r0;
  if (2 * tid + 1 < nn) rowptr[nbase + 2 * tid + 1] = r1;
  __syncthreads();
  for (int e = e0 + tid; e < e1; e += 1024) {
    unsigned ed = part[e];
    int p = atomicAdd(&cnt[ed >> 17], 1);
    col[p] = (int)(ed & 0x1FFFFu);
  }
  if (b == nbuck - 1 && tid == 0) rowptr[n] = pstart[nbuck];
}

// ============ pull-mode mean aggregation, bf16 rows (256 B) ============
// one wave per dst row; half-wave per edge: lanes 0-31 edge j, 32-63 edge j+1.
// lane owns 4 features (uint2); 8-deep unroll => 16 edges in flight per wave.
__global__ __launch_bounds__(256) void gather_mean_bf16(
    const uint2* __restrict__ x, const int* __restrict__ rowptr, const int* __restrict__ col,
    uint2* __restrict__ out, int n) {
  int w = (blockIdx.x * 256 + threadIdx.x) >> 6;
  if (w >= n) return;
  int lane = threadIdx.x & 63;
  int half = lane >> 5, p = lane & 31;
  int s0 = rowptr[w], s1 = rowptr[w + 1];
  float a0 = 0.f, a1 = 0.f, a2 = 0.f, a3 = 0.f;
  int j = s0 + half;
  for (; j + 14 < s1; j += 16) {
    uint2 v[8];
#pragma unroll
    for (int u = 0; u < 8; ++u) {
      int c = col[j + 2 * u];
      v[u] = x[((size_t)c << 5) + p];
    }
#pragma unroll
    for (int u = 0; u < 8; ++u) {
      a0 += bflo(v[u].x); a1 += bfhi(v[u].x);
      a2 += bflo(v[u].y); a3 += bfhi(v[u].y);
    }
  }
  for (; j < s1; j += 2) {
    uint2 v = x[((size_t)col[j] << 5) + p];
    a0 += bflo(v.x); a1 += bfhi(v.x);
    a2 += bflo(v.y); a3 += bfhi(v.y);
  }
  a0 += __shfl_xor(a0, 32); a1 += __shfl_xor(a1, 32);
  a2 += __shfl_xor(a2, 32); a3 += __shfl_xor(a3, 32);
  if (half == 0) {
    float sc = (s1 > s0) ? 1.0f / (float)(s1 - s0) : 0.f;
    uint2 r;
    r.x = (unsigned)f2bf(a0 * sc) | ((unsigned)f2bf(a1 * sc) << 16);
    r.y = (unsigned)f2bf(a2 * sc) | ((unsigned)f2bf(a3 * sc) << 16);
    out[((size_t)w << 5) + p] = r;
  }
}

// ============ weight pre-pack into MFMA A-fragment order ============
__global__ __launch_bounds__(256) void pack_w(const void* __restrict__ Wlv, const void* __restrict__ Wrv,
                                              int wrOff, uint4* __restrict__ dst,
                                              const int* __restrict__ flag) {
  int isb = *flag;
  int t = blockIdx.x * 256 + threadIdx.x;      // 16 blocks x 256 = 4096
  int lane = t & 63, mt = (t >> 6) & 7, ks = t >> 9;
  int feat = mt * 16 + (lane & 15);
  int k0 = ks * 32 + (lane >> 4) * 8;
  unsigned short v[8] __attribute__((aligned(16)));
#pragma unroll
  for (int j = 0; j < 8; ++j) {
    int k = k0 + j;
    int idx = ((k < 128) ? k * 128 : (k - 128) * 128 + wrOff) + feat;
    const void* W = (k < 128) ? Wlv : Wrv;
    v[j] = isb ? ((const unsigned short*)W)[idx] : f2bf(((const float*)W)[idx]);
  }
  dst[t] = *(const uint4*)v;
}

// ============ MFMA conv: out = relu([A|X] @ [Wl;Wr] + b), K=256 ============
__global__ __launch_bounds__(256) void conv_mfma(
    const unsigned short* __restrict__ Abuf, const unsigned short* __restrict__ Xbuf,
    const uint4* __restrict__ Wp, const unsigned short* __restrict__ bias,
    unsigned short* __restrict__ out, int nrows) {
  __shared__ uint4 lds[2048];                  // 32 KB
  int tid = threadIdx.x;
  int row0 = blockIdx.x * 64;

  const char* Ab = (const char*)Abuf;
  const char* Xb = (const char*)Xbuf;
  for (int c = tid; c < 2048; c += 256) {
    int r = c >> 5, seg = c & 31;
    int gr = row0 + r;
    uint4 v = make_uint4(0u, 0u, 0u, 0u);
    if (gr < nrows) {
      const char* srcp = (seg < 16) ? (Ab + (size_t)gr * 256 + seg * 16)
                                    : (Xb + (size_t)gr * 256 + (seg - 16) * 16);
      v = *(const uint4*)srcp;
    }
    int byteoff = (r << 9) + ((seg << 4) ^ ((r & 7) << 4));
    *(uint4*)((char*)lds + byteoff) = v;
  }
  __syncthreads();

  int lane = tid & 63, w = tid >> 6;
  int brow = 16 * w + (lane & 15);
  int q = lane >> 4;
  int q16 = q << 4;

  f32x4 acc[8];
#pragma unroll
  for (int mt = 0; mt < 8; ++mt) acc[mt] = (f32x4){0.f, 0.f, 0.f, 0.f};

  const uint4* wp_lane = Wp + lane;
  int bbase = brow << 9;
  int bxor = (brow & 7) << 4;

  for (int ks = 0; ks < 8; ++ks) {
    int koff = ks * 64 + q16;
    uint4 bv = *(const uint4*)((const char*)lds + bbase + (koff ^ bxor));
    bf16x8 bfrag = __builtin_bit_cast(bf16x8, bv);
#pragma unroll
    for (int mt = 0; mt < 8; ++mt) {
      uint4 av = wp_lane[(ks * 8 + mt) * 64];
      bf16x8 afrag = __builtin_bit_cast(bf16x8, av);
      acc[mt] = __builtin_amdgcn_mfma_f32_16x16x32_bf16(afrag, bfrag, acc[mt], 0, 0, 0);
    }
  }

  int orow = row0 + brow;
  if (orow < nrows) {
    unsigned short* op = out + (size_t)orow * 128;
#pragma unroll
    for (int mt = 0; mt < 8; ++mt) {
      int f0 = mt * 16 + q * 4;
      unsigned b01 = *(const unsigned*)(bias + f0);
      unsigned b23 = *(const unsigned*)(bias + f0 + 2);
      float v0 = fmaxf(acc[mt][0] + bflo(b01), 0.f);
      float v1 = fmaxf(acc[mt][1] + bfhi(b01), 0.f);
      float v2 = fmaxf(acc[mt][2] + bflo(b23), 0.f);
      float v3 = fmaxf(acc[mt][3] + bfhi(b23), 0.f);
      uint2 pk;
      pk.x = (unsigned)f2bf(v0) | ((unsigned)f2bf(v1) << 16);
      pk.y = (unsigned)f2bf(v2) | ((unsigned)f2bf(v3) << 16);
      *(uint2*)(op + f0) = pk;
    }
  }
}

// ============ fused batch mean pool + head (per-graph block) ============
__global__ __launch_bounds__(512) void pool_head(
    const unsigned* __restrict__ hc2, const int* __restrict__ batch_c,
    const unsigned short* __restrict__ WB, void* __restrict__ out,
    const int* __restrict__ flag, int nC) {
  int b = blockIdx.x;
  int tid = threadIdx.x, lane = tid & 63, wv = tid >> 6;

  int lo = 0, hi = nC;
  while (lo < hi) { int m = (lo + hi) >> 1; if (batch_c[m] < b) lo = m + 1; else hi = m; }
  int st = lo;
  hi = nC;
  while (lo < hi) { int m = (lo + hi) >> 1; if (batch_c[m] < b + 1) lo = m + 1; else hi = m; }
  int en = lo;

  float ax = 0.f, ay = 0.f;
  int r = st + wv;
  for (; r + 24 < en; r += 32) {
    unsigned u0 = hc2[((size_t)(r)      << 6) + lane];
    unsigned u1 = hc2[((size_t)(r + 8)  << 6) + lane];
    unsigned u2 = hc2[((size_t)(r + 16) << 6) + lane];
    unsigned u3 = hc2[((size_t)(r + 24) << 6) + lane];
    ax += bflo(u0) + bflo(u1) + bflo(u2) + bflo(u3);
    ay += bfhi(u0) + bfhi(u1) + bfhi(u2) + bfhi(u3);
  }
  for (; r < en; r += 8) {
    unsigned u = hc2[((size_t)r << 6) + lane];
    ax += bflo(u); ay += bfhi(u);
  }

  __shared__ float sg[8][128];
  sg[wv][2 * lane]     = ax;
  sg[wv][2 * lane + 1] = ay;
  __syncthreads();

  __shared__ float gf[128];
  if (tid < 128) {
    float s = 0.f;
#pragma unroll
    for (int i = 0; i < 8; ++i) s += sg[i][tid];
    float sc = (en > st) ? 1.0f / (float)(en - st) : 0.f;
    gf[tid] = s * sc;
  }
  __syncthreads();

  __shared__ float lg[12];
  __shared__ float lse_s;
  if (tid < NCLS) {
    const unsigned short* W    = WB + 768;     // [128][10] bf16
    const unsigned short* bias = WB + 2048;    // [10] bf16
    float acc = bflo((unsigned)bias[tid]);
    for (int k = 0; k < 128; ++k)
      acc += gf[k] * bflo((unsigned)W[k * NCLS + tid]);
    lg[tid] = acc;
  }
  __syncthreads();
  if (tid == 0) {
    float m = lg[0];
    for (int c = 1; c < NCLS; ++c) m = fmaxf(m, lg[c]);
    float se = 0.f;
    for (int c = 0; c < NCLS; ++c) se += expf(lg[c] - m);
    lse_s = logf(se) + m;
  }
  __syncthreads();
  if (tid < NCLS) {
    float o = lg[tid] - lse_s;
    if (*flag) ((unsigned short*)out)[b * NCLS + tid] = f2bf(o);
    else       ((float*)out)[b * NCLS + tid] = o;
  }
}

static void build_csr2(const int* src, const int* dstI, int n, int nE,
                       int* rp, int* colv, unsigned* part,
                       int* bcnt, int* pst, int* bcur, hipStream_t stream) {
  int nbuck = (n + 2047) >> 11;
  int nblk = (nE + PART_BLOCK - 1) / PART_BLOCK;
  bucket_count<<<nblk, 512, 0, stream>>>(dstI, nE, bcnt, nbuck);
  bucket_scan<<<1, 64, 0, stream>>>(bcnt, pst, bcur, nbuck);
  partition_edges<<<nblk, 512, 0, stream>>>(src, dstI, nE, bcur, part, nbuck);
  binned_fill<<<nbuck, 1024, 0, stream>>>(part, pst, rp, colv, n, nbuck);
}

extern "C" void kernel_launch(void* const* d_in, const int* in_sizes, int n_in,
                              void* d_out, int out_size, void* d_ws, size_t ws_size,
                              hipStream_t stream) {
  (void)in_sizes; (void)n_in; (void)out_size; (void)ws_size;
  const void* x        = d_in[0];
  const int*  ei       = (const int*)d_in[1];
  const int*  src      = ei;
  const int*  dst      = ei + N_EDGES;
  const int*  ci       = (const int*)d_in[3];
  const int*  cn       = ci;                // cover: node ids (sources)
  const int*  cc       = ci + N_MEMB;       // cover: cluster ids (dests)
  const int*  eip      = (const int*)d_in[4];
  const int*  srcp     = eip;
  const int*  dstp     = eip + N_EDGESP;
  const int*  batch_c  = (const int*)d_in[5];
  const void* lin2_W   = d_in[6];
  const void* lin2_b   = d_in[7];
  const void* in_c1_Wl = d_in[8];  const void* in_c1_bl = d_in[9];  const void* in_c1_Wr = d_in[10];
  const void* in_c2_Wl = d_in[11]; const void* in_c2_bl = d_in[12]; const void* in_c2_Wr = d_in[13];
  const void* in_lin_W = d_in[14]; const void* in_lin_b = d_in[15];
  const void* b1_c1_Wl = d_in[16]; const void* b1_c1_bl = d_in[17]; const void* b1_c1_Wr = d_in[18];
  const void* b1_c2_Wl = d_in[19]; const void* b1_c2_bl = d_in[20]; const void* b1_c2_Wr = d_in[21];
  const void* b1_lin_W = d_in[22]; const void* b1_lin_b = d_in[23];

  char* base = (char*)d_ws;
  unsigned short* A0 = (unsigned short*)(base + OFF_A0);
  unsigned short* A1 = (unsigned short*)(base + OFF_A1);
  unsigned short* A2 = (unsigned short*)(base + OFF_A2);
  unsigned short* xB = (unsigned short*)(base + OFF_XB);
  uint4* wp0 = (uint4*)(base + OFF_WP);
  unsigned short* WBp = (unsigned short*)(base + OFF_WB);
  int*   ib  = (int*)(base + OFF_IB);
  unsigned* part = (unsigned*)(ib + I_PART);
  int *nrp = ib + I_NRP, *ncol = ib + I_NCOL;
  int *crp = ib + I_CRP, *ccol = ib + I_CCOL;
  int *mrp = ib + I_MRP, *mcol = ib + I_MCOL;
  int *bcnt = ib + I_BCNT;
  int *pst  = ib + I_PST;
  int *bcur = ib + I_BCUR;
  int *flag = ib + I_FLAG;

#define WPK(L) (wp0 + (L) * 4096)

  probe_dtype<<<1, 64, 0, stream>>>((const unsigned short*)x, flag);

  // ---- dtype-generic ingestion: everything -> bf16 ----
  cvt_x<<<6250, 256, 0, stream>>>(x, (uint4*)xB, flag);
  pack_w<<<16, 256, 0, stream>>>(in_c1_Wl, in_c1_Wr, 0,     WPK(0), flag);
  pack_w<<<16, 256, 0, stream>>>(in_c2_Wl, in_c2_Wr, 0,     WPK(1), flag);
  pack_w<<<16, 256, 0, stream>>>(in_lin_W, in_lin_W, 16384, WPK(2), flag);
  pack_w<<<16, 256, 0, stream>>>(b1_c1_Wl, b1_c1_Wr, 0,     WPK(3), flag);
  pack_w<<<16, 256, 0, stream>>>(b1_c2_Wl, b1_c2_Wr, 0,     WPK(4), flag);
  pack_w<<<16, 256, 0, stream>>>(b1_lin_W, b1_lin_W, 16384, WPK(5), flag);
  cvt_small<<<9, 256, 0, stream>>>(in_c1_bl, in_c2_bl, in_lin_b,
                                   b1_c1_bl, b1_c2_bl, b1_lin_b,
                                   lin2_W, lin2_b, WBp, flag);

  // ---- CSRs (binned build; part buffer reused sequentially) ----
  hipMemsetAsync(bcnt, 0, 192 * 4, stream);
  build_csr2(src,  dst,  N_NODES, N_EDGES,  nrp, ncol, part, bcnt,       pst,        bcur,       stream);
  build_csr2(cn,   cc,   N_CLUST, N_MEMB,   mrp, mcol, part, bcnt + 64,  pst + 68,   bcur + 64,  stream);
  build_csr2(srcp, dstp, N_CLUST, N_EDGESP, crp, ccol, part, bcnt + 128, pst + 136,  bcur + 128, stream);

  int gN = (N_NODES + 63) / 64, gC = (N_CLUST + 63) / 64;

  // ---- node block ----
  gather_mean_bf16<<<N_NODES / 4, 256, 0, stream>>>((const uint2*)xB, nrp, ncol, (uint2*)A0, N_NODES);
  conv_mfma<<<gN, 256, 0, stream>>>(A0, xB, WPK(0), WBp + 0,   A1, N_NODES);
  gather_mean_bf16<<<N_NODES / 4, 256, 0, stream>>>((const uint2*)A1, nrp, ncol, (uint2*)A0, N_NODES);
  conv_mfma<<<gN, 256, 0, stream>>>(A0, A1, WPK(1), WBp + 128, A2, N_NODES);
  conv_mfma<<<gN, 256, 0, stream>>>(A1, A2, WPK(2), WBp + 256, A0, N_NODES);     // h -> A0

  // ---- cover pool: h -> hc (A1) ----
  gather_mean_bf16<<<N_CLUST / 4, 256, 0, stream>>>((const uint2*)A0, mrp, mcol, (uint2*)A1, N_CLUST);

  // ---- cluster block ----
  gather_mean_bf16<<<N_CLUST / 4, 256, 0, stream>>>((const uint2*)A1, crp, ccol, (uint2*)A2, N_CLUST);
  conv_mfma<<<gC, 256, 0, stream>>>(A2, A1, WPK(3), WBp + 384, A0, N_CLUST);     // xc1 -> A0
  gather_mean_bf16<<<N_CLUST / 4, 256, 0, stream>>>((const uint2*)A0, crp, ccol, (uint2*)A2, N_CLUST);
  conv_mfma<<<gC, 256, 0, stream>>>(A2, A0, WPK(4), WBp + 512, A1, N_CLUST);     // xc2 -> A1
  conv_mfma<<<gC, 256, 0, stream>>>(A0, A1, WPK(5), WBp + 640, A2, N_CLUST);     // hc2 -> A2

  // ---- fused global mean pool + head ----
  pool_head<<<NB, 512, 0, stream>>>((const unsigned*)A2, batch_c, WBp, d_out, flag, N_CLUST);
}

// Round 8
// 562.103 us; speedup vs baseline: 33.2885x; 1.0046x over previous
//
#include <hip/hip_runtime.h>
#include <hip/hip_bf16.h>

// ---- problem constants ----
#define N_NODES   100000
#define N_EDGES   1600000
#define N_MEMB    150000
#define N_CLUST   40000
#define N_EDGESP  800000
#define NB        64
#define NCLS      10

typedef __attribute__((ext_vector_type(4))) float f32x4;
typedef __attribute__((ext_vector_type(8))) short bf16x8;

// ---- workspace layout (byte offsets) ----
#define OFF_A0   0ul            // bf16 activation arena 0 (100000x128)
#define OFF_A1   25600000ul     // arena 1
#define OFF_A2   51200000ul     // arena 2
#define OFF_XB   76800000ul     // converted-input arena (bf16)
#define OFF_WP   102400000ul    // packed weights: 6 x 65536 B
#define OFF_WB   102793216ul    // converted biases + head weights (bf16)
#define OFF_IB   102801408ul    // int region (16B aligned)
// int region offsets (ints)
#define I_PART  0               // packed edge partition buffer (uint x 1.6M)
#define I_NRP   3200000         // node rowptr 100001
#define I_NCOL  3300004
#define I_CRP   4900004         // cluster rowptr 40001
#define I_CCOL  4940008
#define I_MRP   5740008         // memb rowptr 40001
#define I_MCOL  5780012
#define I_BCNT  5930016         // 3 x 512
#define I_PST   5931552         // 3 x 517
#define I_BCUR  5933103         // 3 x 512
#define I_FLAG  5934639
// end ~5.93M ints => total ws ~126.5 MB

#define PART_BLOCK 4096         // edges per partition block (512 thr x 8)
#define SG_SHIFT   14           // src group = src >> 14 (16K rows = 4 MB bf16 ~ one L2)

__device__ __forceinline__ unsigned short f2bf(float f) {   // RNE round
  unsigned u = __float_as_uint(f);
  return (unsigned short)((u + 0x7FFFu + ((u >> 16) & 1u)) >> 16);
}
__device__ __forceinline__ float bflo(unsigned u) { return __uint_as_float(u << 16); }
__device__ __forceinline__ float bfhi(unsigned u) { return __uint_as_float(u & 0xFFFF0000u); }

// Detect whether "float" inputs are bf16 (flag=1) or f32 (flag=0).
__global__ void probe_dtype(const unsigned short* __restrict__ x, int* __restrict__ flag) {
  if (blockIdx.x != 0 || threadIdx.x != 0) return;
  int wild = 0;
  for (int i = 0; i < 1024; i += 2) {
    int e = (x[i] >> 7) & 0xFF;
    if (e > 0x85) wild++;
  }
  *flag = (wild < 8) ? 1 : 0;
}

// convert external x (f32 or bf16 per flag) -> bf16 arena; 8 elts/thread
__global__ __launch_bounds__(256) void cvt_x(const void* __restrict__ x, uint4* __restrict__ xB,
                                             const int* __restrict__ flag) {
  int gid = blockIdx.x * 256 + threadIdx.x;
  if (gid >= 1600000) return;
  if (*flag) {
    xB[gid] = ((const uint4*)x)[gid];
  } else {
    const float4* xf = (const float4*)x;
    float4 a = xf[2 * gid], b = xf[2 * gid + 1];
    unsigned short v[8] __attribute__((aligned(16)));
    v[0] = f2bf(a.x); v[1] = f2bf(a.y); v[2] = f2bf(a.z); v[3] = f2bf(a.w);
    v[4] = f2bf(b.x); v[5] = f2bf(b.y); v[6] = f2bf(b.z); v[7] = f2bf(b.w);
    xB[gid] = *(const uint4*)v;
  }
}

// ============ merged weight/bias ingestion (one launch) ============
struct PackArgs {
  const void* wl[6];
  const void* wr[6];
  int         wrOff[6];
  const void* bb[6];
  const void* w2;
  const void* b2;
};

// blocks 0..95: pack_w for layer bid>>4 (MFMA A-fragment order);
// block 96: biases + head weights -> bf16 block.
__global__ __launch_bounds__(256) void pack_all(PackArgs pa, uint4* __restrict__ dst,
                                                unsigned short* __restrict__ wb,
                                                const int* __restrict__ flag) {
  int isb = *flag;
  int bid = blockIdx.x;
  if (bid < 96) {
    int L = bid >> 4;
    const void* Wlv = pa.wl[L];
    const void* Wrv = pa.wr[L];
    int wrOff = pa.wrOff[L];
    int t = (bid & 15) * 256 + threadIdx.x;    // 0..4095
    int lane = t & 63, mt = (t >> 6) & 7, ks = t >> 9;
    int feat = mt * 16 + (lane & 15);
    int k0 = ks * 32 + (lane >> 4) * 8;
    unsigned short v[8] __attribute__((aligned(16)));
#pragma unroll
    for (int j = 0; j < 8; ++j) {
      int k = k0 + j;
      int idx = ((k < 128) ? k * 128 : (k - 128) * 128 + wrOff) + feat;
      const void* W = (k < 128) ? Wlv : Wrv;
      v[j] = isb ? ((const unsigned short*)W)[idx] : f2bf(((const float*)W)[idx]);
    }
    dst[L * 4096 + t] = *(const uint4*)v;
  } else {
    for (int gid = threadIdx.x; gid < 2058; gid += 256) {
      const void* src; int local;
      if (gid < 768) { int seg = gid >> 7; local = gid & 127; src = pa.bb[seg]; }
      else if (gid < 2048) { src = pa.w2; local = gid - 768; }
      else { src = pa.b2; local = gid - 2048; }
      wb[gid] = isb ? ((const unsigned short*)src)[local] : f2bf(((const float*)src)[local]);
    }
  }
}

// ============ binned CSR build with (dst_bucket x src_group) partitions ============
// partition index = (dst>>11)*ng + (src>>SG_SHIFT); npart = nbuck*ng <= 512.

__global__ __launch_bounds__(512) void bucket_count(const int* __restrict__ srcI,
                                                    const int* __restrict__ dstI, int nE,
                                                    int* __restrict__ bcnt, int ng) {
  __shared__ int h[512];
  int tid = threadIdx.x;
  h[tid] = 0;
  __syncthreads();
  int base = blockIdx.x * PART_BLOCK + tid;
#pragma unroll
  for (int j = 0; j < 8; ++j) {
    int i = base + j * 512;
    if (i < nE) atomicAdd(&h[(dstI[i] >> 11) * ng + (srcI[i] >> SG_SHIFT)], 1);
  }
  __syncthreads();
  if (h[tid]) atomicAdd(&bcnt[tid], h[tid]);
}

// exclusive scan of bcnt[0..n) -> pstart[0..n], init bcur = pstart (n <= 512)
__global__ __launch_bounds__(512) void bucket_scan(const int* __restrict__ bcnt,
                                                   int* __restrict__ pstart,
                                                   int* __restrict__ bcur, int n) {
  __shared__ int ws[8];
  int tid = threadIdx.x, lane = tid & 63, wv = tid >> 6;
  int v = (tid < n) ? bcnt[tid] : 0;
  int inc = v;
  for (int off = 1; off < 64; off <<= 1) {
    int u = __shfl_up(inc, off);
    if (lane >= off) inc += u;
  }
  if (lane == 63) ws[wv] = inc;
  __syncthreads();
  int woff = 0;
  for (int k = 0; k < wv; ++k) woff += ws[k];
  int ex = woff + inc - v;
  if (tid < n) { pstart[tid] = ex; bcur[tid] = ex; }
  if (tid == n - 1) pstart[n] = ex + v;
}

// scatter packed (src | local_dst<<17) into per-partition ranges
__global__ __launch_bounds__(512) void partition_edges(
    const int* __restrict__ srcI, const int* __restrict__ dstI, int nE,
    int* __restrict__ bcur, unsigned* __restrict__ part, int ng) {
  __shared__ int h[512], lcur[512];
  int tid = threadIdx.x;
  h[tid] = 0;
  __syncthreads();
  int base = blockIdx.x * PART_BLOCK + tid;
  int s[8], d[8], bk[8];
#pragma unroll
  for (int j = 0; j < 8; ++j) {
    int i = base + j * 512;
    if (i < nE) {
      d[j] = dstI[i]; s[j] = srcI[i];
      bk[j] = (d[j] >> 11) * ng + (s[j] >> SG_SHIFT);
      atomicAdd(&h[bk[j]], 1);
    } else bk[j] = -1;
  }
  __syncthreads();
  if (h[tid]) lcur[tid] = atomicAdd(&bcur[tid], h[tid]);
  __syncthreads();
#pragma unroll
  for (int j = 0; j < 8; ++j) {
    if (bk[j] >= 0) {
      int p = atomicAdd(&lcur[bk[j]], 1);
      part[p] = (unsigned)s[j] | ((unsigned)(d[j] & 2047) << 17);
    }
  }
}

// one workgroup per dst bucket: LDS histogram -> scan -> rowptr, then scatter
// col GROUP-SEQUENTIALLY so each row's list is ordered by src group.
__global__ __launch_bounds__(1024) void binned_fill(
    const unsigned* __restrict__ part, const int* __restrict__ pstart,
    int* __restrict__ rowptr, int* __restrict__ col, int n, int nbuck, int ng) {
  __shared__ int cnt[2048];
  __shared__ int wsum[16];
  int b = blockIdx.x, tid = threadIdx.x;
  int nbase = b << 11;
  int nn = n - nbase; if (nn > 2048) nn = 2048;
  cnt[tid] = 0; cnt[tid + 1024] = 0;
  __syncthreads();
  int e0 = pstart[b * ng], e1 = pstart[(b + 1) * ng];
  for (int e = e0 + tid; e < e1; e += 1024)
    atomicAdd(&cnt[part[e] >> 17], 1);
  __syncthreads();
  int c0 = cnt[2 * tid], c1 = cnt[2 * tid + 1];
  int s = c0 + c1;
  int lane = tid & 63, wv = tid >> 6;
  int inc = s;
  for (int off = 1; off < 64; off <<= 1) {
    int u = __shfl_up(inc, off);
    if (lane >= off) inc += u;
  }
  if (lane == 63) wsum[wv] = inc;
  __syncthreads();
  int woff = 0;
  for (int k = 0; k < wv; ++k) woff += wsum[k];
  int excl = woff + (inc - s);
  int r0 = e0 + excl;
  int r1 = r0 + c0;
  __syncthreads();
  cnt[2 * tid] = r0; cnt[2 * tid + 1] = r1;
  if (2 * tid < nn)     rowptr[nbase + 2 * tid]     = r0;
  if (2 * tid + 1 < nn) rowptr[nbase + 2 * tid + 1] = r1;
  __syncthreads();
  for (int g = 0; g < ng; ++g) {
    int f0 = pstart[b * ng + g], f1 = pstart[b * ng + g + 1];
    for (int e = f0 + tid; e < f1; e += 1024) {
      unsigned ed = part[e];
      int p = atomicAdd(&cnt[ed >> 17], 1);
      col[p] = (int)(ed & 0x1FFFFu);
    }
    __syncthreads();
  }
  if (b == nbuck - 1 && tid == 0) rowptr[n] = pstart[nbuck * ng];
}

// ============ pull-mode mean aggregation, bf16 rows (256 B) ============
// one wave per dst row; half-wave per edge; col lists are src-group ordered
// so concurrently-resident waves share an L2-sized source window.
__global__ __launch_bounds__(256) void gather_mean_bf16(
    const uint2* __restrict__ x, const int* __restrict__ rowptr, const int* __restrict__ col,
    uint2* __restrict__ out, int n) {
  int w = (blockIdx.x * 256 + threadIdx.x) >> 6;
  if (w >= n) return;
  int lane = threadIdx.x & 63;
  int half = lane >> 5, p = lane & 31;
  int s0 = rowptr[w], s1 = rowptr[w + 1];
  float a0 = 0.f, a1 = 0.f, a2 = 0.f, a3 = 0.f;
  int j = s0 + half;
  for (; j + 14 < s1; j += 16) {
    uint2 v[8];
#pragma unroll
    for (int u = 0; u < 8; ++u) {
      int c = col[j + 2 * u];
      v[u] = x[((size_t)c << 5) + p];
    }
#pragma unroll
    for (int u = 0; u < 8; ++u) {
      a0 += bflo(v[u].x); a1 += bfhi(v[u].x);
      a2 += bflo(v[u].y); a3 += bfhi(v[u].y);
    }
  }
  for (; j < s1; j += 2) {
    uint2 v = x[((size_t)col[j] << 5) + p];
    a0 += bflo(v.x); a1 += bfhi(v.x);
    a2 += bflo(v.y); a3 += bfhi(v.y);
  }
  a0 += __shfl_xor(a0, 32); a1 += __shfl_xor(a1, 32);
  a2 += __shfl_xor(a2, 32); a3 += __shfl_xor(a3, 32);
  if (half == 0) {
    float sc = (s1 > s0) ? 1.0f / (float)(s1 - s0) : 0.f;
    uint2 r;
    r.x = (unsigned)f2bf(a0 * sc) | ((unsigned)f2bf(a1 * sc) << 16);
    r.y = (unsigned)f2bf(a2 * sc) | ((unsigned)f2bf(a3 * sc) << 16);
    out[((size_t)w << 5) + p] = r;
  }
}

// ============ MFMA conv: out = relu([A|X] @ [Wl;Wr] + b), K=256 ============
__global__ __launch_bounds__(256) void conv_mfma(
    const unsigned short* __restrict__ Abuf, const unsigned short* __restrict__ Xbuf,
    const uint4* __restrict__ Wp, const unsigned short* __restrict__ bias,
    unsigned short* __restrict__ out, int nrows) {
  __shared__ uint4 lds[2048];                  // 32 KB
  int tid = threadIdx.x;
  int row0 = blockIdx.x * 64;

  const char* Ab = (const char*)Abuf;
  const char* Xb = (const char*)Xbuf;
  for (int c = tid; c < 2048; c += 256) {
    int r = c >> 5, seg = c & 31;
    int gr = row0 + r;
    uint4 v = make_uint4(0u, 0u, 0u, 0u);
    if (gr < nrows) {
      const char* srcp = (seg < 16) ? (Ab + (size_t)gr * 256 + seg * 16)
                                    : (Xb + (size_t)gr * 256 + (seg - 16) * 16);
      v = *(const uint4*)srcp;
    }
    int byteoff = (r << 9) + ((seg << 4) ^ ((r & 7) << 4));
    *(uint4*)((char*)lds + byteoff) = v;
  }
  __syncthreads();

  int lane = tid & 63, w = tid >> 6;
  int brow = 16 * w + (lane & 15);
  int q = lane >> 4;
  int q16 = q << 4;

  f32x4 acc[8];
#pragma unroll
  for (int mt = 0; mt < 8; ++mt) acc[mt] = (f32x4){0.f, 0.f, 0.f, 0.f};

  const uint4* wp_lane = Wp + lane;
  int bbase = brow << 9;
  int bxor = (brow & 7) << 4;

  for (int ks = 0; ks < 8; ++ks) {
    int koff = ks * 64 + q16;
    uint4 bv = *(const uint4*)((const char*)lds + bbase + (koff ^ bxor));
    bf16x8 bfrag = __builtin_bit_cast(bf16x8, bv);
#pragma unroll
    for (int mt = 0; mt < 8; ++mt) {
      uint4 av = wp_lane[(ks * 8 + mt) * 64];
      bf16x8 afrag = __builtin_bit_cast(bf16x8, av);
      acc[mt] = __builtin_amdgcn_mfma_f32_16x16x32_bf16(afrag, bfrag, acc[mt], 0, 0, 0);
    }
  }

  int orow = row0 + brow;
  if (orow < nrows) {
    unsigned short* op = out + (size_t)orow * 128;
#pragma unroll
    for (int mt = 0; mt < 8; ++mt) {
      int f0 = mt * 16 + q * 4;
      unsigned b01 = *(const unsigned*)(bias + f0);
      unsigned b23 = *(const unsigned*)(bias + f0 + 2);
      float v0 = fmaxf(acc[mt][0] + bflo(b01), 0.f);
      float v1 = fmaxf(acc[mt][1] + bfhi(b01), 0.f);
      float v2 = fmaxf(acc[mt][2] + bflo(b23), 0.f);
      float v3 = fmaxf(acc[mt][3] + bfhi(b23), 0.f);
      uint2 pk;
      pk.x = (unsigned)f2bf(v0) | ((unsigned)f2bf(v1) << 16);
      pk.y = (unsigned)f2bf(v2) | ((unsigned)f2bf(v3) << 16);
      *(uint2*)(op + f0) = pk;
    }
  }
}

// ============ fused batch mean pool + head (per-graph block) ============
__global__ __launch_bounds__(512) void pool_head(
    const unsigned* __restrict__ hc2, const int* __restrict__ batch_c,
    const unsigned short* __restrict__ WB, void* __restrict__ out,
    const int* __restrict__ flag, int nC) {
  int b = blockIdx.x;
  int tid = threadIdx.x, lane = tid & 63, wv = tid >> 6;

  int lo = 0, hi = nC;
  while (lo < hi) { int m = (lo + hi) >> 1; if (batch_c[m] < b) lo = m + 1; else hi = m; }
  int st = lo;
  hi = nC;
  while (lo < hi) { int m = (lo + hi) >> 1; if (batch_c[m] < b + 1) lo = m + 1; else hi = m; }
  int en = lo;

  float ax = 0.f, ay = 0.f;
  int r = st + wv;
  for (; r + 24 < en; r += 32) {
    unsigned u0 = hc2[((size_t)(r)      << 6) + lane];
    unsigned u1 = hc2[((size_t)(r + 8)  << 6) + lane];
    unsigned u2 = hc2[((size_t)(r + 16) << 6) + lane];
    unsigned u3 = hc2[((size_t)(r + 24) << 6) + lane];
    ax += bflo(u0) + bflo(u1) + bflo(u2) + bflo(u3);
    ay += bfhi(u0) + bfhi(u1) + bfhi(u2) + bfhi(u3);
  }
  for (; r < en; r += 8) {
    unsigned u = hc2[((size_t)r << 6) + lane];
    ax += bflo(u); ay += bfhi(u);
  }

  __shared__ float sg[8][128];
  sg[wv][2 * lane]     = ax;
  sg[wv][2 * lane + 1] = ay;
  __syncthreads();

  __shared__ float gf[128];
  if (tid < 128) {
    float s = 0.f;
#pragma unroll
    for (int i = 0; i < 8; ++i) s += sg[i][tid];
    float sc = (en > st) ? 1.0f / (float)(en - st) : 0.f;
    gf[tid] = s * sc;
  }
  __syncthreads();

  __shared__ float lg[12];
  __shared__ float lse_s;
  if (tid < NCLS) {
    const unsigned short* W    = WB + 768;     // [128][10] bf16
    const unsigned short* bias = WB + 2048;    // [10] bf16
    float acc = bflo((unsigned)bias[tid]);
    for (int k = 0; k < 128; ++k)
      acc += gf[k] * bflo((unsigned)W[k * NCLS + tid]);
    lg[tid] = acc;
  }
  __syncthreads();
  if (tid == 0) {
    float m = lg[0];
    for (int c = 1; c < NCLS; ++c) m = fmaxf(m, lg[c]);
    float se = 0.f;
    for (int c = 0; c < NCLS; ++c) se += expf(lg[c] - m);
    lse_s = logf(se) + m;
  }
  __syncthreads();
  if (tid < NCLS) {
    float o = lg[tid] - lse_s;
    if (*flag) ((unsigned short*)out)[b * NCLS + tid] = f2bf(o);
    else       ((float*)out)[b * NCLS + tid] = o;
  }
}

static void build_csr2(const int* src, const int* dstI, int n, int nsrc, int nE,
                       int* rp, int* colv, unsigned* part,
                       int* bcnt, int* pst, int* bcur, hipStream_t stream) {
  int nbuck = (n + 2047) >> 11;
  int ng = (nsrc + (1 << SG_SHIFT) - 1) >> SG_SHIFT;
  int npart = nbuck * ng;                      // <= 512 by construction
  int nblk = (nE + PART_BLOCK - 1) / PART_BLOCK;
  bucket_count<<<nblk, 512, 0, stream>>>(src, dstI, nE, bcnt, ng);
  bucket_scan<<<1, 512, 0, stream>>>(bcnt, pst, bcur, npart);
  partition_edges<<<nblk, 512, 0, stream>>>(src, dstI, nE, bcur, part, ng);
  binned_fill<<<nbuck, 1024, 0, stream>>>(part, pst, rp, colv, n, nbuck, ng);
}

extern "C" void kernel_launch(void* const* d_in, const int* in_sizes, int n_in,
                              void* d_out, int out_size, void* d_ws, size_t ws_size,
                              hipStream_t stream) {
  (void)in_sizes; (void)n_in; (void)out_size; (void)ws_size;
  const void* x        = d_in[0];
  const int*  ei       = (const int*)d_in[1];
  const int*  src      = ei;
  const int*  dst      = ei + N_EDGES;
  const int*  ci       = (const int*)d_in[3];
  const int*  cn       = ci;                // cover: node ids (sources)
  const int*  cc       = ci + N_MEMB;       // cover: cluster ids (dests)
  const int*  eip      = (const int*)d_in[4];
  const int*  srcp     = eip;
  const int*  dstp     = eip + N_EDGESP;
  const int*  batch_c  = (const int*)d_in[5];

  PackArgs pa;
  pa.wl[0] = d_in[8];  pa.wr[0] = d_in[10]; pa.wrOff[0] = 0;     pa.bb[0] = d_in[9];
  pa.wl[1] = d_in[11]; pa.wr[1] = d_in[13]; pa.wrOff[1] = 0;     pa.bb[1] = d_in[12];
  pa.wl[2] = d_in[14]; pa.wr[2] = d_in[14]; pa.wrOff[2] = 16384; pa.bb[2] = d_in[15];
  pa.wl[3] = d_in[16]; pa.wr[3] = d_in[18]; pa.wrOff[3] = 0;     pa.bb[3] = d_in[17];
  pa.wl[4] = d_in[19]; pa.wr[4] = d_in[21]; pa.wrOff[4] = 0;     pa.bb[4] = d_in[20];
  pa.wl[5] = d_in[22]; pa.wr[5] = d_in[22]; pa.wrOff[5] = 16384; pa.bb[5] = d_in[23];
  pa.w2 = d_in[6]; pa.b2 = d_in[7];

  char* base = (char*)d_ws;
  unsigned short* A0 = (unsigned short*)(base + OFF_A0);
  unsigned short* A1 = (unsigned short*)(base + OFF_A1);
  unsigned short* A2 = (unsigned short*)(base + OFF_A2);
  unsigned short* xB = (unsigned short*)(base + OFF_XB);
  uint4* wp0 = (uint4*)(base + OFF_WP);
  unsigned short* WBp = (unsigned short*)(base + OFF_WB);
  int*   ib  = (int*)(base + OFF_IB);
  unsigned* part = (unsigned*)(ib + I_PART);
  int *nrp = ib + I_NRP, *ncol = ib + I_NCOL;
  int *crp = ib + I_CRP, *ccol = ib + I_CCOL;
  int *mrp = ib + I_MRP, *mcol = ib + I_MCOL;
  int *bcnt = ib + I_BCNT;                  // 3 x 512
  int *pst  = ib + I_PST;                   // 3 x 517
  int *bcur = ib + I_BCUR;                  // 3 x 512
  int *flag = ib + I_FLAG;

#define WPK(L) (wp0 + (L) * 4096)

  probe_dtype<<<1, 64, 0, stream>>>((const unsigned short*)x, flag);

  // ---- dtype-generic ingestion: everything -> bf16 ----
  cvt_x<<<6250, 256, 0, stream>>>(x, (uint4*)xB, flag);
  pack_all<<<97, 256, 0, stream>>>(pa, wp0, WBp, flag);

  // ---- CSRs (binned, src-grouped build; part buffer reused sequentially) ----
  hipMemsetAsync(bcnt, 0, 3 * 512 * 4, stream);
  build_csr2(src,  dst,  N_NODES, N_NODES, N_EDGES,  nrp, ncol, part, bcnt,        pst,        bcur,        stream);
  build_csr2(cn,   cc,   N_CLUST, N_NODES, N_MEMB,   mrp, mcol, part, bcnt + 512,  pst + 517,  bcur + 512,  stream);
  build_csr2(srcp, dstp, N_CLUST, N_CLUST, N_EDGESP, crp, ccol, part, bcnt + 1024, pst + 1034, bcur + 1024, stream);

  int gN = (N_NODES + 63) / 64, gC = (N_CLUST + 63) / 64;

  // ---- node block ----
  gather_mean_bf16<<<N_NODES / 4, 256, 0, stream>>>((const uint2*)xB, nrp, ncol, (uint2*)A0, N_NODES);
  conv_mfma<<<gN, 256, 0, stream>>>(A0, xB, WPK(0), WBp + 0,   A1, N_NODES);
  gather_mean_bf16<<<N_NODES / 4, 256, 0, stream>>>((const uint2*)A1, nrp, ncol, (uint2*)A0, N_NODES);
  conv_mfma<<<gN, 256, 0, stream>>>(A0, A1, WPK(1), WBp + 128, A2, N_NODES);
  conv_mfma<<<gN, 256, 0, stream>>>(A1, A2, WPK(2), WBp + 256, A0, N_NODES);     // h -> A0

  // ---- cover pool: h -> hc (A1) ----
  gather_mean_bf16<<<N_CLUST / 4, 256, 0, stream>>>((const uint2*)A0, mrp, mcol, (uint2*)A1, N_CLUST);

  // ---- cluster block ----
  gather_mean_bf16<<<N_CLUST / 4, 256, 0, stream>>>((const uint2*)A1, crp, ccol, (uint2*)A2, N_CLUST);
  conv_mfma<<<gC, 256, 0, stream>>>(A2, A1, WPK(3), WBp + 384, A0, N_CLUST);     // xc1 -> A0
  gather_mean_bf16<<<N_CLUST / 4, 256, 0, stream>>>((const uint2*)A0, crp, ccol, (uint2*)A2, N_CLUST);
  conv_mfma<<<gC, 256, 0, stream>>>(A2, A0, WPK(4), WBp + 512, A1, N_CLUST);     // xc2 -> A1
  conv_mfma<<<gC, 256, 0, stream>>>(A0, A1, WPK(5), WBp + 640, A2, N_CLUST);     // hc2 -> A2

  // ---- fused global mean pool + head ----
  pool_head<<<NB, 512, 0, stream>>>((const unsigned*)A2, batch_c, WBp, d_out, flag, N_CLUST);
}